// Round 1
// baseline (10282.703 us; speedup 1.0000x reference)
//
#include <hip/hip_runtime.h>

#define HEADS 4
#define CH 64
#define HC 256
#define NGRAPH 32
#define NEG_ATT 0.2f
#define NEG_ACT 0.01f

// ---------- helpers: monotonic float<->uint mapping for atomicMax ----------
__device__ __forceinline__ unsigned flip_f(float f) {
  unsigned u = __float_as_uint(f);
  return (u & 0x80000000u) ? ~u : (u | 0x80000000u);
}
__device__ __forceinline__ float unflip_f(unsigned u) {
  return (u & 0x80000000u) ? __uint_as_float(u ^ 0x80000000u)
                           : __uint_as_float(~u);
}

// ---------- GEMM: Y[n,m] = sum_k lrelu?(X[n,k]) * W[m,k] + bias[m], M=256 ----------
// 64x64 tile per block, 16x16 threads, 4x4 micro-tile, K-tile 16.
__global__ __launch_bounds__(256) void gemm_bias(
    const float* __restrict__ X, const float* __restrict__ W,
    const float* __restrict__ bias, float* __restrict__ Y,
    int N, int K, int relu_in) {
  __shared__ float Xs[16][65];
  __shared__ float Ws[16][65];
  const int tid = threadIdx.y * 16 + threadIdx.x;
  const int row0 = blockIdx.x * 64;
  const int col0 = blockIdx.y * 64;
  float acc[4][4] = {};
  for (int k0 = 0; k0 < K; k0 += 16) {
#pragma unroll
    for (int i = 0; i < 4; i++) {
      int e = tid + i * 256;       // 0..1023
      int r = e >> 4;              // 0..63
      int kk = e & 15;
      int gr = row0 + r;
      float xv = (gr < N) ? X[(size_t)gr * K + k0 + kk] : 0.f;
      if (relu_in) xv = xv > 0.f ? xv : NEG_ACT * xv;
      Xs[kk][r] = xv;
      Ws[kk][r] = W[(size_t)(col0 + r) * K + k0 + kk];
    }
    __syncthreads();
#pragma unroll
    for (int kk = 0; kk < 16; kk++) {
      float xr_[4], wr_[4];
#pragma unroll
      for (int i = 0; i < 4; i++) xr_[i] = Xs[kk][threadIdx.y * 4 + i];
#pragma unroll
      for (int j = 0; j < 4; j++) wr_[j] = Ws[kk][threadIdx.x * 4 + j];
#pragma unroll
      for (int i = 0; i < 4; i++)
#pragma unroll
        for (int j = 0; j < 4; j++) acc[i][j] = fmaf(xr_[i], wr_[j], acc[i][j]);
    }
    __syncthreads();
  }
#pragma unroll
  for (int i = 0; i < 4; i++) {
    int gr = row0 + threadIdx.y * 4 + i;
    if (gr >= N) continue;
#pragma unroll
    for (int j = 0; j < 4; j++) {
      int gc = col0 + threadIdx.x * 4 + j;
      Y[(size_t)gr * HC + gc] = acc[i][j] + bias[gc];
    }
  }
}

// ---------- edge pass 1: score + segment max (one wave per edge) ----------
__global__ __launch_bounds__(256) void edge_score(
    const float* __restrict__ xl, const float* __restrict__ xr,
    const int* __restrict__ esrc, const int* __restrict__ edst,
    const float* __restrict__ att, float* __restrict__ score,
    unsigned* __restrict__ mflip, int Etot, int Eorig) {
  int gtid = blockIdx.x * 256 + threadIdx.x;
  int e = gtid >> 6;
  int lane = threadIdx.x & 63;
  if (e >= Etot) return;
  int src, dst;
  if (e < Eorig) { src = esrc[e]; dst = edst[e]; }
  else { src = e - Eorig; dst = src; }
  int h = lane >> 4;
  int c4 = (lane & 15) * 4;
  const float4 a = *(const float4*)&att[h * CH + c4];
  const float4 lv = *(const float4*)&xl[(size_t)src * HC + h * CH + c4];
  const float4 rv = *(const float4*)&xr[(size_t)dst * HC + h * CH + c4];
  float t, s0 = 0.f;
  t = lv.x + rv.x; t = t > 0.f ? t : NEG_ATT * t; s0 = fmaf(t, a.x, s0);
  t = lv.y + rv.y; t = t > 0.f ? t : NEG_ATT * t; s0 = fmaf(t, a.y, s0);
  t = lv.z + rv.z; t = t > 0.f ? t : NEG_ATT * t; s0 = fmaf(t, a.z, s0);
  t = lv.w + rv.w; t = t > 0.f ? t : NEG_ATT * t; s0 = fmaf(t, a.w, s0);
#pragma unroll
  for (int off = 1; off < 16; off <<= 1) s0 += __shfl_xor(s0, off);
  if ((lane & 15) == 0) {
    score[(size_t)e * HEADS + h] = s0;
    atomicMax(&mflip[(size_t)dst * HEADS + h], flip_f(s0));
  }
}

// ---------- edge pass 2: p = exp(score - m[dst]); s += p ----------
__global__ __launch_bounds__(256) void alpha_sum(
    float* __restrict__ score, const int* __restrict__ edst,
    const unsigned* __restrict__ mflip, float* __restrict__ ssum,
    int Etot, int Eorig) {
  int idx = blockIdx.x * 256 + threadIdx.x;
  if (idx >= Etot * HEADS) return;
  int e = idx >> 2;
  int h = idx & 3;
  int dst = (e < Eorig) ? edst[e] : e - Eorig;
  float m = unflip_f(mflip[(size_t)dst * HEADS + h]);
  float p = __expf(score[idx] - m);
  score[idx] = p;
  atomicAdd(&ssum[(size_t)dst * HEADS + h], p);
}

// ---------- init out with bias ----------
__global__ __launch_bounds__(256) void init_bias(
    float* __restrict__ out, const float* __restrict__ bo, int N) {
  int idx = blockIdx.x * 256 + threadIdx.x;
  out[idx] = bo[idx & (HC - 1)];
}

// ---------- edge pass 3: out[dst] += (p/s[dst]) * xl[src] ----------
__global__ __launch_bounds__(256) void aggregate(
    const float* __restrict__ xl, const float* __restrict__ score,
    const float* __restrict__ ssum, const int* __restrict__ esrc,
    const int* __restrict__ edst, float* __restrict__ out,
    int Etot, int Eorig) {
  int gtid = blockIdx.x * 256 + threadIdx.x;
  int e = gtid >> 6;
  int lane = threadIdx.x & 63;
  if (e >= Etot) return;
  int src, dst;
  if (e < Eorig) { src = esrc[e]; dst = edst[e]; }
  else { src = e - Eorig; dst = src; }
  int h = lane >> 4;
  int c4 = (lane & 15) * 4;
  float alpha = score[(size_t)e * HEADS + h] / ssum[(size_t)dst * HEADS + h];
  const float4 lv = *(const float4*)&xl[(size_t)src * HC + h * CH + c4];
  float* op = &out[(size_t)dst * HC + h * CH + c4];
  atomicAdd(op + 0, alpha * lv.x);
  atomicAdd(op + 1, alpha * lv.y);
  atomicAdd(op + 2, alpha * lv.z);
  atomicAdd(op + 3, alpha * lv.w);
}

// ---------- pooling stage 1: per-block per-graph partial sums ----------
__global__ __launch_bounds__(256) void pool_partial(
    const float* __restrict__ h, const int* __restrict__ batch,
    float* __restrict__ out, int* __restrict__ cnt, int N) {
  __shared__ float part[NGRAPH][HC];
  __shared__ int bsh[256];
  __shared__ int cpart[NGRAPH];
  int j = threadIdx.x;
#pragma unroll
  for (int g = 0; g < NGRAPH; g++) part[g][j] = 0.f;
  if (j < NGRAPH) cpart[j] = 0;
  int n0 = blockIdx.x * 256;
  int nend = min(n0 + 256, N);
  int nj = n0 + j;
  bsh[j] = (nj < N) ? batch[nj] : 0;
  __syncthreads();
  if (nj < nend) atomicAdd(&cpart[bsh[j]], 1);
  for (int n = n0; n < nend; n++) {
    int g = bsh[n - n0];
    part[g][j] += h[(size_t)n * HC + j];
  }
  __syncthreads();
#pragma unroll
  for (int g = 0; g < NGRAPH; g++) {
    float v = part[g][j];
    if (v != 0.f) atomicAdd(&out[g * HC + j], v);
  }
  if (j < NGRAPH && cpart[j] > 0) atomicAdd(&cnt[j], cpart[j]);
}

// ---------- pooling stage 2: divide by counts ----------
__global__ __launch_bounds__(256) void pool_final(
    float* __restrict__ out, const int* __restrict__ cnt) {
  int g = blockIdx.x;
  int j = threadIdx.x;
  float c = (float)max(cnt[g], 1);
  out[g * HC + j] /= c;
}

extern "C" void kernel_launch(void* const* d_in, const int* in_sizes, int n_in,
                              void* d_out, int out_size, void* d_ws, size_t ws_size,
                              hipStream_t stream) {
  const float* x = (const float*)d_in[0];
  const int* ei = (const int*)d_in[1];
  const int* batch = (const int*)d_in[2];
  const int N = in_sizes[2];
  const int E = in_sizes[1] / 2;
  const int Etot = E + N;

  const float* Wl[3] = {(const float*)d_in[3], (const float*)d_in[9], (const float*)d_in[15]};
  const float* bl[3] = {(const float*)d_in[4], (const float*)d_in[10], (const float*)d_in[16]};
  const float* Wr[3] = {(const float*)d_in[5], (const float*)d_in[11], (const float*)d_in[17]};
  const float* br[3] = {(const float*)d_in[6], (const float*)d_in[12], (const float*)d_in[18]};
  const float* att[3] = {(const float*)d_in[7], (const float*)d_in[13], (const float*)d_in[19]};
  const float* bo[3] = {(const float*)d_in[8], (const float*)d_in[14], (const float*)d_in[20]};

  float* B0 = (float*)d_ws;                          // node features / layer out
  float* B1 = B0 + (size_t)N * HC;                   // xl
  float* B2 = B1 + (size_t)N * HC;                   // xr
  float* score = B2 + (size_t)N * HC;                // Etot*H
  unsigned* mflip = (unsigned*)(score + (size_t)Etot * HEADS);  // N*H
  float* ssum = (float*)(mflip + (size_t)N * HEADS); // N*H
  int* cnt = (int*)(ssum + (size_t)N * HEADS);       // NGRAPH

  const int* esrc = ei;
  const int* edst = ei + E;

  const dim3 gblk(16, 16);
  const int eblocks = (Etot + 3) / 4;             // one wave (64 lanes) per edge
  const int ablocks = (Etot * HEADS + 255) / 256; // one thread per (edge,head)

  for (int l = 0; l < 3; l++) {
    const float* Xin = (l == 0) ? x : B0;
    const int K = (l == 0) ? 128 : HC;
    const int relu_in = (l == 0) ? 0 : 1;
    dim3 ggrid((N + 63) / 64, HC / 64);
    gemm_bias<<<ggrid, gblk, 0, stream>>>(Xin, Wl[l], bl[l], B1, N, K, relu_in);
    gemm_bias<<<ggrid, gblk, 0, stream>>>(Xin, Wr[l], br[l], B2, N, K, relu_in);
    (void)hipMemsetAsync(mflip, 0, (size_t)N * HEADS * sizeof(unsigned), stream);
    (void)hipMemsetAsync(ssum, 0, (size_t)N * HEADS * sizeof(float), stream);
    edge_score<<<eblocks, 256, 0, stream>>>(B1, B2, esrc, edst, att[l], score, mflip, Etot, E);
    alpha_sum<<<ablocks, 256, 0, stream>>>(score, edst, mflip, ssum, Etot, E);
    init_bias<<<N, 256, 0, stream>>>(B0, bo[l], N);
    aggregate<<<eblocks, 256, 0, stream>>>(B1, score, ssum, esrc, edst, B0, Etot, E);
  }

  (void)hipMemsetAsync(d_out, 0, NGRAPH * HC * sizeof(float), stream);
  (void)hipMemsetAsync(cnt, 0, NGRAPH * sizeof(int), stream);
  pool_partial<<<(N + 255) / 256, 256, 0, stream>>>(B0, batch, (float*)d_out, cnt, N);
  pool_final<<<NGRAPH, 256, 0, stream>>>((float*)d_out, cnt);
}

// Round 2
// 1497.174 us; speedup vs baseline: 6.8681x; 6.8681x over previous
//
#include <hip/hip_runtime.h>

#define HEADS 4
#define CH 64
#define HC 256
#define NGRAPH 32
#define NEG_ATT 0.2f
#define NEG_ACT 0.01f

// ---------- GEMM: Y[n,m] = sum_k lrelu?(X[n,k]) * W[m,k] + bias[m], M=256 ----------
__global__ __launch_bounds__(256) void gemm_bias(
    const float* __restrict__ X, const float* __restrict__ W,
    const float* __restrict__ bias, float* __restrict__ Y,
    int N, int K, int relu_in) {
  __shared__ float Xs[16][65];
  __shared__ float Ws[16][65];
  const int tid = threadIdx.y * 16 + threadIdx.x;
  const int row0 = blockIdx.x * 64;
  const int col0 = blockIdx.y * 64;
  float acc[4][4] = {};
  for (int k0 = 0; k0 < K; k0 += 16) {
#pragma unroll
    for (int i = 0; i < 4; i++) {
      int e = tid + i * 256;
      int r = e >> 4;
      int kk = e & 15;
      int gr = row0 + r;
      float xv = (gr < N) ? X[(size_t)gr * K + k0 + kk] : 0.f;
      if (relu_in) xv = xv > 0.f ? xv : NEG_ACT * xv;
      Xs[kk][r] = xv;
      Ws[kk][r] = W[(size_t)(col0 + r) * K + k0 + kk];
    }
    __syncthreads();
#pragma unroll
    for (int kk = 0; kk < 16; kk++) {
      float xr_[4], wr_[4];
#pragma unroll
      for (int i = 0; i < 4; i++) xr_[i] = Xs[kk][threadIdx.y * 4 + i];
#pragma unroll
      for (int j = 0; j < 4; j++) wr_[j] = Ws[kk][threadIdx.x * 4 + j];
#pragma unroll
      for (int i = 0; i < 4; i++)
#pragma unroll
        for (int j = 0; j < 4; j++) acc[i][j] = fmaf(xr_[i], wr_[j], acc[i][j]);
    }
    __syncthreads();
  }
#pragma unroll
  for (int i = 0; i < 4; i++) {
    int gr = row0 + threadIdx.y * 4 + i;
    if (gr >= N) continue;
#pragma unroll
    for (int j = 0; j < 4; j++) {
      int gc = col0 + threadIdx.x * 4 + j;
      Y[(size_t)gr * HC + gc] = acc[i][j] + bias[gc];
    }
  }
}

// ---------- CSR build ----------
__global__ __launch_bounds__(256) void set_ones(int* __restrict__ counts, int N) {
  int i = blockIdx.x * 256 + threadIdx.x;
  if (i < N) counts[i] = 1;  // self-loop
}

__global__ __launch_bounds__(256) void hist_dst(
    const int* __restrict__ edst, int* __restrict__ counts, int E) {
  int e = blockIdx.x * 256 + threadIdx.x;
  if (e < E) atomicAdd(&counts[edst[e]], 1);
}

// single-block chunked inclusive scan -> exclusive row_start
__global__ __launch_bounds__(1024) void scan_counts(
    const int* __restrict__ counts, int* __restrict__ row_start, int N) {
  __shared__ int tmp[1024];
  __shared__ int carry_s;
  int t = threadIdx.x;
  if (t == 0) { carry_s = 0; row_start[0] = 0; }
  __syncthreads();
  for (int base = 0; base < N; base += 1024) {
    int i = base + t;
    int v = (i < N) ? counts[i] : 0;
    tmp[t] = v;
    __syncthreads();
    for (int off = 1; off < 1024; off <<= 1) {
      int add = (t >= off) ? tmp[t - off] : 0;
      __syncthreads();
      tmp[t] += add;
      __syncthreads();
    }
    int carry = carry_s;
    if (i < N) row_start[i + 1] = carry + tmp[t];
    __syncthreads();
    if (t == 1023) carry_s = carry + tmp[1023];
    __syncthreads();
  }
}

__global__ __launch_bounds__(256) void csr_init(
    const int* __restrict__ row_start, int* __restrict__ fill_pos,
    int* __restrict__ csr_src, int N) {
  int i = blockIdx.x * 256 + threadIdx.x;
  if (i < N) {
    int p = row_start[i];
    csr_src[p] = i;          // self-loop first
    fill_pos[i] = p + 1;
  }
}

__global__ __launch_bounds__(256) void csr_scatter(
    const int* __restrict__ esrc, const int* __restrict__ edst,
    int* __restrict__ fill_pos, int* __restrict__ csr_src, int E) {
  int e = blockIdx.x * 256 + threadIdx.x;
  if (e < E) {
    int p = atomicAdd(&fill_pos[edst[e]], 1);
    csr_src[p] = esrc[e];
  }
}

// ---------- fused GATv2 edge phase: one wave per dst, online softmax ----------
__global__ __launch_bounds__(256) void gat_fused(
    const float* __restrict__ xl, const float* __restrict__ xr,
    const int* __restrict__ row_start, const int* __restrict__ csr_src,
    const float* __restrict__ att, const float* __restrict__ bo,
    float* __restrict__ out, int N) {
  int dst = (blockIdx.x * 256 + threadIdx.x) >> 6;
  int lane = threadIdx.x & 63;
  if (dst >= N) return;
  int h = lane >> 4;
  int c4 = (lane & 15) * 4;
  const float4 a = *(const float4*)&att[h * CH + c4];
  const float4 rv = *(const float4*)&xr[(size_t)dst * HC + h * CH + c4];
  float4 o = {0.f, 0.f, 0.f, 0.f};
  float m = -__builtin_inff();
  float s = 0.f;
  int beg = row_start[dst];
  int end = row_start[dst + 1];
  for (int p = beg; p < end; p++) {
    int src = csr_src[p];
    const float4 lv = *(const float4*)&xl[(size_t)src * HC + h * CH + c4];
    float t, d = 0.f;
    t = lv.x + rv.x; t = t > 0.f ? t : NEG_ATT * t; d = fmaf(t, a.x, d);
    t = lv.y + rv.y; t = t > 0.f ? t : NEG_ATT * t; d = fmaf(t, a.y, d);
    t = lv.z + rv.z; t = t > 0.f ? t : NEG_ATT * t; d = fmaf(t, a.z, d);
    t = lv.w + rv.w; t = t > 0.f ? t : NEG_ATT * t; d = fmaf(t, a.w, d);
    // reduce over the 16 lanes of this head
    d += __shfl_xor(d, 1);
    d += __shfl_xor(d, 2);
    d += __shfl_xor(d, 4);
    d += __shfl_xor(d, 8);
    float newm = fmaxf(m, d);
    float scale = __expf(m - newm);   // first iter: exp(-inf)=0
    float pe = __expf(d - newm);
    s = s * scale + pe;
    o.x = o.x * scale + pe * lv.x;
    o.y = o.y * scale + pe * lv.y;
    o.z = o.z * scale + pe * lv.z;
    o.w = o.w * scale + pe * lv.w;
    m = newm;
  }
  float inv = 1.f / s;
  const float4 b4 = *(const float4*)&bo[h * CH + c4];
  float4 res;
  res.x = o.x * inv + b4.x;
  res.y = o.y * inv + b4.y;
  res.z = o.z * inv + b4.z;
  res.w = o.w * inv + b4.w;
  *(float4*)&out[(size_t)dst * HC + h * CH + c4] = res;
}

// ---------- pooling ----------
__global__ __launch_bounds__(256) void pool_partial(
    const float* __restrict__ h, const int* __restrict__ batch,
    float* __restrict__ out, int* __restrict__ cnt, int N) {
  __shared__ float part[NGRAPH][HC];
  __shared__ int bsh[256];
  __shared__ int cpart[NGRAPH];
  int j = threadIdx.x;
#pragma unroll
  for (int g = 0; g < NGRAPH; g++) part[g][j] = 0.f;
  if (j < NGRAPH) cpart[j] = 0;
  int n0 = blockIdx.x * 256;
  int nend = min(n0 + 256, N);
  int nj = n0 + j;
  bsh[j] = (nj < N) ? batch[nj] : 0;
  __syncthreads();
  if (nj < nend) atomicAdd(&cpart[bsh[j]], 1);
  for (int n = n0; n < nend; n++) {
    int g = bsh[n - n0];
    part[g][j] += h[(size_t)n * HC + j];
  }
  __syncthreads();
#pragma unroll
  for (int g = 0; g < NGRAPH; g++) {
    float v = part[g][j];
    if (v != 0.f) atomicAdd(&out[g * HC + j], v);
  }
  if (j < NGRAPH && cpart[j] > 0) atomicAdd(&cnt[j], cpart[j]);
}

__global__ __launch_bounds__(256) void pool_final(
    float* __restrict__ out, const int* __restrict__ cnt) {
  int g = blockIdx.x;
  int j = threadIdx.x;
  float c = (float)max(cnt[g], 1);
  out[g * HC + j] /= c;
}

extern "C" void kernel_launch(void* const* d_in, const int* in_sizes, int n_in,
                              void* d_out, int out_size, void* d_ws, size_t ws_size,
                              hipStream_t stream) {
  const float* x = (const float*)d_in[0];
  const int* ei = (const int*)d_in[1];
  const int* batch = (const int*)d_in[2];
  const int N = in_sizes[2];
  const int E = in_sizes[1] / 2;
  const int Etot = E + N;

  const float* Wl[3] = {(const float*)d_in[3], (const float*)d_in[9], (const float*)d_in[15]};
  const float* bl[3] = {(const float*)d_in[4], (const float*)d_in[10], (const float*)d_in[16]};
  const float* Wr[3] = {(const float*)d_in[5], (const float*)d_in[11], (const float*)d_in[17]};
  const float* br[3] = {(const float*)d_in[6], (const float*)d_in[12], (const float*)d_in[18]};
  const float* att[3] = {(const float*)d_in[7], (const float*)d_in[13], (const float*)d_in[19]};
  const float* bo[3] = {(const float*)d_in[8], (const float*)d_in[14], (const float*)d_in[20]};

  float* B0 = (float*)d_ws;                          // node features / layer out
  float* B1 = B0 + (size_t)N * HC;                   // xl
  float* B2 = B1 + (size_t)N * HC;                   // xr
  int* counts = (int*)(B2 + (size_t)N * HC);         // N
  int* row_start = counts + N;                       // N+1
  int* fill_pos = row_start + N + 1;                 // N
  int* csr_src = fill_pos + N;                       // Etot
  int* cnt = csr_src + Etot;                         // NGRAPH

  const int* esrc = ei;
  const int* edst = ei + E;

  // ---- CSR build (per call; ws is re-poisoned every launch) ----
  set_ones<<<(N + 255) / 256, 256, 0, stream>>>(counts, N);
  hist_dst<<<(E + 255) / 256, 256, 0, stream>>>(edst, counts, E);
  scan_counts<<<1, 1024, 0, stream>>>(counts, row_start, N);
  csr_init<<<(N + 255) / 256, 256, 0, stream>>>(row_start, fill_pos, csr_src, N);
  csr_scatter<<<(E + 255) / 256, 256, 0, stream>>>(esrc, edst, fill_pos, csr_src, E);

  const dim3 gblk(16, 16);
  const int fblocks = (N * 64 + 255) / 256;  // one wave per dst

  for (int l = 0; l < 3; l++) {
    const float* Xin = (l == 0) ? x : B0;
    const int K = (l == 0) ? 128 : HC;
    const int relu_in = (l == 0) ? 0 : 1;
    dim3 ggrid((N + 63) / 64, HC / 64);
    gemm_bias<<<ggrid, gblk, 0, stream>>>(Xin, Wl[l], bl[l], B1, N, K, relu_in);
    gemm_bias<<<ggrid, gblk, 0, stream>>>(Xin, Wr[l], br[l], B2, N, K, relu_in);
    gat_fused<<<fblocks, 256, 0, stream>>>(B1, B2, row_start, csr_src, att[l], bo[l], B0, N);
  }

  (void)hipMemsetAsync(d_out, 0, NGRAPH * HC * sizeof(float), stream);
  (void)hipMemsetAsync(cnt, 0, NGRAPH * sizeof(int), stream);
  pool_partial<<<(N + 255) / 256, 256, 0, stream>>>(B0, batch, (float*)d_out, cnt, N);
  pool_final<<<NGRAPH, 256, 0, stream>>>((float*)d_out, cnt);
}

// Round 3
// 1082.031 us; speedup vs baseline: 9.5031x; 1.3837x over previous
//
#include <hip/hip_runtime.h>

#define HEADS 4
#define CH 64
#define HC 256
#define NGRAPH 32
#define NEG_ATT 0.2f
#define NEG_ACT 0.01f

typedef __attribute__((ext_vector_type(8))) short bf16x8;
typedef __attribute__((ext_vector_type(4))) float f32x4;

// split two fp32 into packed hi-bf16 pair and lo-bf16 pair (truncation; lo captures residual)
__device__ __forceinline__ void split2(float a, float b, unsigned& hi, unsigned& lo) {
  unsigned ua = __float_as_uint(a), ub = __float_as_uint(b);
  float la = a - __uint_as_float(ua & 0xFFFF0000u);
  float lb = b - __uint_as_float(ub & 0xFFFF0000u);
  hi = __builtin_amdgcn_perm(ub, ua, 0x07060302u);  // [hi16(b) : hi16(a)]
  lo = __builtin_amdgcn_perm(__float_as_uint(lb), __float_as_uint(la), 0x07060302u);
}

// ---------- MFMA GEMM: Y[n,m] = sum_k lrelu?(X[n,k]) * W[m,k] + bias[m] ----------
// 128x128 tile, 4 waves, each wave 64x64 (4x4 MFMA 16x16x32), split-bf16 3-term emulation.
__global__ __launch_bounds__(256) void gemm_mfma(
    const float* __restrict__ X, const float* __restrict__ W,
    const float* __restrict__ bias, float* __restrict__ Y,
    int N, int K, int relu_in) {
  __shared__ unsigned short Ahi[128][40];
  __shared__ unsigned short Alo[128][40];
  __shared__ unsigned short Bhi[128][40];
  __shared__ unsigned short Blo[128][40];

  const int tid = threadIdx.x;
  const int wave = tid >> 6;
  const int lane = tid & 63;
  const int quad = lane >> 4;
  const int l16 = lane & 15;
  const int wr = (wave >> 1) * 64;   // wave's row offset in tile
  const int wc = (wave & 1) * 64;    // wave's col offset in tile
  const int row0 = blockIdx.x * 128;
  const int col0 = blockIdx.y * 128;

  f32x4 acc[4][4];
#pragma unroll
  for (int i = 0; i < 4; i++)
#pragma unroll
    for (int j = 0; j < 4; j++) acc[i][j] = (f32x4){0.f, 0.f, 0.f, 0.f};

  for (int k0 = 0; k0 < K; k0 += 32) {
    __syncthreads();
    // stage A and B tiles: 128 rows x 32 k each; 1024 16B-chunks per matrix
#pragma unroll
    for (int it = 0; it < 4; it++) {
      int g = tid + it * 256;
      int r = g >> 3;
      int c4 = (g & 7) * 4;
      int gr = row0 + r;
      if (gr >= N) gr = N - 1;
      float4 v = *(const float4*)&X[(size_t)gr * K + k0 + c4];
      if (relu_in) {
        v.x = v.x > 0.f ? v.x : NEG_ACT * v.x;
        v.y = v.y > 0.f ? v.y : NEG_ACT * v.y;
        v.z = v.z > 0.f ? v.z : NEG_ACT * v.z;
        v.w = v.w > 0.f ? v.w : NEG_ACT * v.w;
      }
      uint2 h2, l2;
      split2(v.x, v.y, h2.x, l2.x);
      split2(v.z, v.w, h2.y, l2.y);
      *(uint2*)&Ahi[r][c4] = h2;
      *(uint2*)&Alo[r][c4] = l2;

      const float4 wv = *(const float4*)&W[(size_t)(col0 + r) * K + k0 + c4];
      uint2 wh2, wl2;
      split2(wv.x, wv.y, wh2.x, wl2.x);
      split2(wv.z, wv.w, wh2.y, wl2.y);
      *(uint2*)&Bhi[r][c4] = wh2;
      *(uint2*)&Blo[r][c4] = wl2;
    }
    __syncthreads();

    bf16x8 ahi[4], alo[4], bhi[4], blo[4];
#pragma unroll
    for (int i = 0; i < 4; i++) {
      ahi[i] = *(const bf16x8*)&Ahi[wr + i * 16 + l16][quad * 8];
      alo[i] = *(const bf16x8*)&Alo[wr + i * 16 + l16][quad * 8];
      bhi[i] = *(const bf16x8*)&Bhi[wc + i * 16 + l16][quad * 8];
      blo[i] = *(const bf16x8*)&Blo[wc + i * 16 + l16][quad * 8];
    }
#pragma unroll
    for (int i = 0; i < 4; i++)
#pragma unroll
      for (int j = 0; j < 4; j++) {
        acc[i][j] = __builtin_amdgcn_mfma_f32_16x16x32_bf16(ahi[i], bhi[j], acc[i][j], 0, 0, 0);
        acc[i][j] = __builtin_amdgcn_mfma_f32_16x16x32_bf16(ahi[i], blo[j], acc[i][j], 0, 0, 0);
        acc[i][j] = __builtin_amdgcn_mfma_f32_16x16x32_bf16(alo[i], bhi[j], acc[i][j], 0, 0, 0);
      }
  }

  // epilogue: D row = m = quad*4+reg, col = n = lane&15
#pragma unroll
  for (int j = 0; j < 4; j++) {
    int col = col0 + wc + j * 16 + l16;
    float b = bias[col];
#pragma unroll
    for (int i = 0; i < 4; i++) {
#pragma unroll
      for (int r = 0; r < 4; r++) {
        int row = row0 + wr + i * 16 + quad * 4 + r;
        if (row < N) Y[(size_t)row * HC + col] = acc[i][j][r] + b;
      }
    }
  }
}

// ---------- CSR build ----------
__global__ __launch_bounds__(256) void set_ones(int* __restrict__ counts, int N) {
  int i = blockIdx.x * 256 + threadIdx.x;
  if (i < N) counts[i] = 1;  // self-loop
}

__global__ __launch_bounds__(256) void hist_dst(
    const int* __restrict__ edst, int* __restrict__ counts, int E) {
  int e = blockIdx.x * 256 + threadIdx.x;
  if (e < E) atomicAdd(&counts[edst[e]], 1);
}

__global__ __launch_bounds__(1024) void scan_counts(
    const int* __restrict__ counts, int* __restrict__ row_start, int N) {
  __shared__ int tmp[1024];
  __shared__ int carry_s;
  int t = threadIdx.x;
  if (t == 0) { carry_s = 0; row_start[0] = 0; }
  __syncthreads();
  for (int base = 0; base < N; base += 1024) {
    int i = base + t;
    int v = (i < N) ? counts[i] : 0;
    tmp[t] = v;
    __syncthreads();
    for (int off = 1; off < 1024; off <<= 1) {
      int add = (t >= off) ? tmp[t - off] : 0;
      __syncthreads();
      tmp[t] += add;
      __syncthreads();
    }
    int carry = carry_s;
    if (i < N) row_start[i + 1] = carry + tmp[t];
    __syncthreads();
    if (t == 1023) carry_s = carry + tmp[1023];
    __syncthreads();
  }
}

__global__ __launch_bounds__(256) void csr_init(
    const int* __restrict__ row_start, int* __restrict__ fill_pos,
    int* __restrict__ csr_src, int N) {
  int i = blockIdx.x * 256 + threadIdx.x;
  if (i < N) {
    int p = row_start[i];
    csr_src[p] = i;  // self-loop first
    fill_pos[i] = p + 1;
  }
}

__global__ __launch_bounds__(256) void csr_scatter(
    const int* __restrict__ esrc, const int* __restrict__ edst,
    int* __restrict__ fill_pos, int* __restrict__ csr_src, int E) {
  int e = blockIdx.x * 256 + threadIdx.x;
  if (e < E) {
    int p = atomicAdd(&fill_pos[edst[e]], 1);
    csr_src[p] = esrc[e];
  }
}

// ---------- fused GATv2 edge phase: one wave per dst, online softmax ----------
__global__ __launch_bounds__(256) void gat_fused(
    const float* __restrict__ xl, const float* __restrict__ xr,
    const int* __restrict__ row_start, const int* __restrict__ csr_src,
    const float* __restrict__ att, const float* __restrict__ bo,
    float* __restrict__ out, int N) {
  int dst = (blockIdx.x * 256 + threadIdx.x) >> 6;
  int lane = threadIdx.x & 63;
  if (dst >= N) return;
  int h = lane >> 4;
  int c4 = (lane & 15) * 4;
  const float4 a = *(const float4*)&att[h * CH + c4];
  const float4 rv = *(const float4*)&xr[(size_t)dst * HC + h * CH + c4];
  float4 o = {0.f, 0.f, 0.f, 0.f};
  float m = -__builtin_inff();
  float s = 0.f;
  int beg = row_start[dst];
  int end = row_start[dst + 1];
  for (int p = beg; p < end; p++) {
    int src = csr_src[p];
    const float4 lv = *(const float4*)&xl[(size_t)src * HC + h * CH + c4];
    float t, d = 0.f;
    t = lv.x + rv.x; t = t > 0.f ? t : NEG_ATT * t; d = fmaf(t, a.x, d);
    t = lv.y + rv.y; t = t > 0.f ? t : NEG_ATT * t; d = fmaf(t, a.y, d);
    t = lv.z + rv.z; t = t > 0.f ? t : NEG_ATT * t; d = fmaf(t, a.z, d);
    t = lv.w + rv.w; t = t > 0.f ? t : NEG_ATT * t; d = fmaf(t, a.w, d);
    d += __shfl_xor(d, 1);
    d += __shfl_xor(d, 2);
    d += __shfl_xor(d, 4);
    d += __shfl_xor(d, 8);
    float newm = fmaxf(m, d);
    float scale = __expf(m - newm);
    float pe = __expf(d - newm);
    s = s * scale + pe;
    o.x = o.x * scale + pe * lv.x;
    o.y = o.y * scale + pe * lv.y;
    o.z = o.z * scale + pe * lv.z;
    o.w = o.w * scale + pe * lv.w;
    m = newm;
  }
  float inv = 1.f / s;
  const float4 b4 = *(const float4*)&bo[h * CH + c4];
  float4 res;
  res.x = o.x * inv + b4.x;
  res.y = o.y * inv + b4.y;
  res.z = o.z * inv + b4.z;
  res.w = o.w * inv + b4.w;
  *(float4*)&out[(size_t)dst * HC + h * CH + c4] = res;
}

// ---------- pooling ----------
__global__ __launch_bounds__(256) void pool_partial(
    const float* __restrict__ h, const int* __restrict__ batch,
    float* __restrict__ out, int* __restrict__ cnt, int N) {
  __shared__ float part[NGRAPH][HC];
  __shared__ int bsh[256];
  __shared__ int cpart[NGRAPH];
  int j = threadIdx.x;
#pragma unroll
  for (int g = 0; g < NGRAPH; g++) part[g][j] = 0.f;
  if (j < NGRAPH) cpart[j] = 0;
  int n0 = blockIdx.x * 256;
  int nend = min(n0 + 256, N);
  int nj = n0 + j;
  bsh[j] = (nj < N) ? batch[nj] : 0;
  __syncthreads();
  if (nj < nend) atomicAdd(&cpart[bsh[j]], 1);
  for (int n = n0; n < nend; n++) {
    int g = bsh[n - n0];
    part[g][j] += h[(size_t)n * HC + j];
  }
  __syncthreads();
#pragma unroll
  for (int g = 0; g < NGRAPH; g++) {
    float v = part[g][j];
    if (v != 0.f) atomicAdd(&out[g * HC + j], v);
  }
  if (j < NGRAPH && cpart[j] > 0) atomicAdd(&cnt[j], cpart[j]);
}

__global__ __launch_bounds__(256) void pool_final(
    float* __restrict__ out, const int* __restrict__ cnt) {
  int g = blockIdx.x;
  int j = threadIdx.x;
  float c = (float)max(cnt[g], 1);
  out[g * HC + j] /= c;
}

extern "C" void kernel_launch(void* const* d_in, const int* in_sizes, int n_in,
                              void* d_out, int out_size, void* d_ws, size_t ws_size,
                              hipStream_t stream) {
  const float* x = (const float*)d_in[0];
  const int* ei = (const int*)d_in[1];
  const int* batch = (const int*)d_in[2];
  const int N = in_sizes[2];
  const int E = in_sizes[1] / 2;
  const int Etot = E + N;

  const float* Wl[3] = {(const float*)d_in[3], (const float*)d_in[9], (const float*)d_in[15]};
  const float* bl[3] = {(const float*)d_in[4], (const float*)d_in[10], (const float*)d_in[16]};
  const float* Wr[3] = {(const float*)d_in[5], (const float*)d_in[11], (const float*)d_in[17]};
  const float* br[3] = {(const float*)d_in[6], (const float*)d_in[12], (const float*)d_in[18]};
  const float* att[3] = {(const float*)d_in[7], (const float*)d_in[13], (const float*)d_in[19]};
  const float* bo[3] = {(const float*)d_in[8], (const float*)d_in[14], (const float*)d_in[20]};

  float* B0 = (float*)d_ws;                          // node features / layer out
  float* B1 = B0 + (size_t)N * HC;                   // xl
  float* B2 = B1 + (size_t)N * HC;                   // xr
  int* counts = (int*)(B2 + (size_t)N * HC);         // N
  int* row_start = counts + N;                       // N+1
  int* fill_pos = row_start + N + 1;                 // N
  int* csr_src = fill_pos + N;                       // Etot
  int* cnt = csr_src + Etot;                         // NGRAPH

  const int* esrc = ei;
  const int* edst = ei + E;

  // ---- CSR build (per call; ws is re-poisoned every launch) ----
  set_ones<<<(N + 255) / 256, 256, 0, stream>>>(counts, N);
  hist_dst<<<(E + 255) / 256, 256, 0, stream>>>(edst, counts, E);
  scan_counts<<<1, 1024, 0, stream>>>(counts, row_start, N);
  csr_init<<<(N + 255) / 256, 256, 0, stream>>>(row_start, fill_pos, csr_src, N);
  csr_scatter<<<(E + 255) / 256, 256, 0, stream>>>(esrc, edst, fill_pos, csr_src, E);

  const int fblocks = (N * 64 + 255) / 256;  // one wave per dst

  for (int l = 0; l < 3; l++) {
    const float* Xin = (l == 0) ? x : B0;
    const int K = (l == 0) ? 128 : HC;
    const int relu_in = (l == 0) ? 0 : 1;
    dim3 ggrid((N + 127) / 128, HC / 128);
    gemm_mfma<<<ggrid, 256, 0, stream>>>(Xin, Wl[l], bl[l], B1, N, K, relu_in);
    gemm_mfma<<<ggrid, 256, 0, stream>>>(Xin, Wr[l], br[l], B2, N, K, relu_in);
    gat_fused<<<fblocks, 256, 0, stream>>>(B1, B2, row_start, csr_src, att[l], bo[l], B0, N);
  }

  (void)hipMemsetAsync(d_out, 0, NGRAPH * HC * sizeof(float), stream);
  (void)hipMemsetAsync(cnt, 0, NGRAPH * sizeof(int), stream);
  pool_partial<<<(N + 255) / 256, 256, 0, stream>>>(B0, batch, (float*)d_out, cnt, N);
  pool_final<<<NGRAPH, 256, 0, stream>>>((float*)d_out, cnt);
}

// Round 4
// 893.126 us; speedup vs baseline: 11.5132x; 1.2115x over previous
//
#include <hip/hip_runtime.h>

#define HEADS 4
#define CH 64
#define HC 256
#define NGRAPH 32
#define NEG_ATT 0.2f
#define NEG_ACT 0.01f

typedef __attribute__((ext_vector_type(8))) short bf16x8;
typedef __attribute__((ext_vector_type(4))) float f32x4;

// split two fp32 into packed hi-bf16 pair and lo-bf16 pair (truncation; lo captures residual)
__device__ __forceinline__ void split2(float a, float b, unsigned& hi, unsigned& lo) {
  unsigned ua = __float_as_uint(a), ub = __float_as_uint(b);
  float la = a - __uint_as_float(ua & 0xFFFF0000u);
  float lb = b - __uint_as_float(ub & 0xFFFF0000u);
  hi = __builtin_amdgcn_perm(ub, ua, 0x07060302u);  // [hi16(b) : hi16(a)]
  lo = __builtin_amdgcn_perm(__float_as_uint(lb), __float_as_uint(la), 0x07060302u);
}

// ---------- one-time conversions to split-bf16 planes ----------
__global__ __launch_bounds__(256) void convert_x(
    const float* __restrict__ X, unsigned short* __restrict__ xhi,
    unsigned short* __restrict__ xlo, int total4) {
  int g = blockIdx.x * 256 + threadIdx.x;
  if (g >= total4) return;
  float4 v = *(const float4*)&X[(size_t)g * 4];
  uint2 h2, l2;
  split2(v.x, v.y, h2.x, l2.x);
  split2(v.z, v.w, h2.y, l2.y);
  *(uint2*)&xhi[(size_t)g * 4] = h2;
  *(uint2*)&xlo[(size_t)g * 4] = l2;
}

// W' = [Wl; Wr] (512 x K) -> hi/lo planes
__global__ __launch_bounds__(256) void convert_w(
    const float* __restrict__ Wl, const float* __restrict__ Wr,
    unsigned short* __restrict__ whi, unsigned short* __restrict__ wlo, int K) {
  int g = blockIdx.x * 256 + threadIdx.x;  // 512*K/4 threads
  int e4 = g * 4;
  int half = 256 * K;
  const float* src = (e4 < half) ? &Wl[e4] : &Wr[e4 - half];
  float4 v = *(const float4*)src;
  uint2 h2, l2;
  split2(v.x, v.y, h2.x, l2.x);
  split2(v.z, v.w, h2.y, l2.y);
  *(uint2*)&whi[(size_t)e4] = h2;
  *(uint2*)&wlo[(size_t)e4] = l2;
}

// ---------- fused MFMA GEMM: Y1|Y2 [n, 256|256] = X(hi/lo) @ W'(hi/lo)^T + bias ----------
// 128 rows x 128 cols per block, 4 waves (2x2 of 64x64), 16x16x32 bf16 MFMA x 3 terms.
__global__ __launch_bounds__(256) void gemm_fused(
    const unsigned short* __restrict__ xhi, const unsigned short* __restrict__ xlo,
    const unsigned short* __restrict__ whi, const unsigned short* __restrict__ wlo,
    const float* __restrict__ bl, const float* __restrict__ br,
    float* __restrict__ Y1, float* __restrict__ Y2, int N, int K) {
  __shared__ unsigned short Ahi[128][32];
  __shared__ unsigned short Alo[128][32];
  __shared__ unsigned short Bhi[128][32];
  __shared__ unsigned short Blo[128][32];

  const int tid = threadIdx.x;
  const int wave = tid >> 6;
  const int lane = tid & 63;
  const int quad = lane >> 4;
  const int l16 = lane & 15;
  const int wr = (wave >> 1) * 64;
  const int wc = (wave & 1) * 64;
  const int col0 = blockIdx.x * 128;  // grid.x = 4 -> cols 0..511 of W'
  const int row0 = blockIdx.y * 128;

  f32x4 acc[4][4];
#pragma unroll
  for (int i = 0; i < 4; i++)
#pragma unroll
    for (int j = 0; j < 4; j++) acc[i][j] = (f32x4){0.f, 0.f, 0.f, 0.f};

  const int r_s = tid >> 2;       // 0..63
  const int c_s = (tid & 3) * 8;  // ushort offset of 16B chunk

  for (int k0 = 0; k0 < K; k0 += 32) {
#pragma unroll
    for (int it = 0; it < 2; it++) {
      int r = r_s + it * 64;
      int gr = row0 + r;
      if (gr >= N) gr = N - 1;
      size_t ga = (size_t)gr * K + k0 + c_s;
      *(uint4*)&Ahi[r][c_s] = *(const uint4*)&xhi[ga];
      *(uint4*)&Alo[r][c_s] = *(const uint4*)&xlo[ga];
      size_t gb = (size_t)(col0 + r) * K + k0 + c_s;
      *(uint4*)&Bhi[r][c_s] = *(const uint4*)&whi[gb];
      *(uint4*)&Blo[r][c_s] = *(const uint4*)&wlo[gb];
    }
    __syncthreads();

    bf16x8 ahi[4], alo[4], bhi[4], blo[4];
#pragma unroll
    for (int i = 0; i < 4; i++) {
      ahi[i] = *(const bf16x8*)&Ahi[wr + i * 16 + l16][quad * 8];
      alo[i] = *(const bf16x8*)&Alo[wr + i * 16 + l16][quad * 8];
      bhi[i] = *(const bf16x8*)&Bhi[wc + i * 16 + l16][quad * 8];
      blo[i] = *(const bf16x8*)&Blo[wc + i * 16 + l16][quad * 8];
    }
#pragma unroll
    for (int i = 0; i < 4; i++)
#pragma unroll
      for (int j = 0; j < 4; j++) {
        acc[i][j] = __builtin_amdgcn_mfma_f32_16x16x32_bf16(ahi[i], bhi[j], acc[i][j], 0, 0, 0);
        acc[i][j] = __builtin_amdgcn_mfma_f32_16x16x32_bf16(ahi[i], blo[j], acc[i][j], 0, 0, 0);
        acc[i][j] = __builtin_amdgcn_mfma_f32_16x16x32_bf16(alo[i], bhi[j], acc[i][j], 0, 0, 0);
      }
    __syncthreads();
  }

  // epilogue: D row = quad*4+reg, col = l16 (validated mapping)
#pragma unroll
  for (int j = 0; j < 4; j++) {
    int colg = col0 + wc + j * 16 + l16;  // 0..511
    float bv;
    float* Yp;
    int cc;
    if (colg < HC) { bv = bl[colg]; Yp = Y1; cc = colg; }
    else           { bv = br[colg - HC]; Yp = Y2; cc = colg - HC; }
#pragma unroll
    for (int i = 0; i < 4; i++) {
#pragma unroll
      for (int r = 0; r < 4; r++) {
        int row = row0 + wr + i * 16 + quad * 4 + r;
        if (row < N) Yp[(size_t)row * HC + cc] = acc[i][j][r] + bv;
      }
    }
  }
}

// ---------- CSR build ----------
__global__ __launch_bounds__(256) void set_ones(int* __restrict__ counts, int N) {
  int i = blockIdx.x * 256 + threadIdx.x;
  if (i < N) counts[i] = 1;  // self-loop
}

__global__ __launch_bounds__(256) void hist_dst(
    const int* __restrict__ edst, int* __restrict__ counts, int E) {
  int e = blockIdx.x * 256 + threadIdx.x;
  if (e < E) atomicAdd(&counts[edst[e]], 1);
}

// hierarchical scan: per-1024-chunk block scan -> 1-wave top scan -> add offsets
__global__ __launch_bounds__(256) void scan_blocks(
    const int* __restrict__ counts, int* __restrict__ row_start,
    int* __restrict__ bsum, int N) {
  __shared__ int tmp[256];
  int t = threadIdx.x;
  int base = blockIdx.x * 1024 + t * 4;
  int v0 = (base     < N) ? counts[base]     : 0;
  int v1 = (base + 1 < N) ? counts[base + 1] : 0;
  int v2 = (base + 2 < N) ? counts[base + 2] : 0;
  int v3 = (base + 3 < N) ? counts[base + 3] : 0;
  int c1 = v0 + v1, c2 = c1 + v2, tot = c2 + v3;
  tmp[t] = tot;
  __syncthreads();
  for (int off = 1; off < 256; off <<= 1) {
    int add = (t >= off) ? tmp[t - off] : 0;
    __syncthreads();
    tmp[t] += add;
    __syncthreads();
  }
  int excl = tmp[t] - tot;
  if (base     < N) row_start[base + 1] = excl + v0;
  if (base + 1 < N) row_start[base + 2] = excl + c1;
  if (base + 2 < N) row_start[base + 3] = excl + c2;
  if (base + 3 < N) row_start[base + 4] = excl + tot;
  if (t == 255) bsum[blockIdx.x] = tmp[255];
  if (blockIdx.x == 0 && t == 0) row_start[0] = 0;
}

__global__ void scan_tops(int* __restrict__ bsum, int nb) {
  int lane = threadIdx.x;  // 64 threads, 1 block; nb <= 64
  int v = (lane < nb) ? bsum[lane] : 0;
  for (int off = 1; off < 64; off <<= 1) {
    int u = __shfl_up(v, off);
    if (lane >= off) v += u;
  }
  if (lane < nb) bsum[lane] = v;  // inclusive
}

__global__ __launch_bounds__(256) void scan_add(
    int* __restrict__ row_start, const int* __restrict__ bsum, int N) {
  int off = bsum[blockIdx.x];                     // incl sum of chunks 0..blockIdx.x
  int i = (blockIdx.x + 1) * 1024 + threadIdx.x * 4;
#pragma unroll
  for (int k = 0; k < 4; k++)
    if (i + k < N) row_start[i + k + 1] += off;
}

__global__ __launch_bounds__(256) void csr_init(
    const int* __restrict__ row_start, int* __restrict__ fill_pos,
    int* __restrict__ csr_src, int N) {
  int i = blockIdx.x * 256 + threadIdx.x;
  if (i < N) {
    int p = row_start[i];
    csr_src[p] = i;  // self-loop first
    fill_pos[i] = p + 1;
  }
}

__global__ __launch_bounds__(256) void csr_scatter(
    const int* __restrict__ esrc, const int* __restrict__ edst,
    int* __restrict__ fill_pos, int* __restrict__ csr_src, int E) {
  int e = blockIdx.x * 256 + threadIdx.x;
  if (e < E) {
    int p = atomicAdd(&fill_pos[edst[e]], 1);
    csr_src[p] = esrc[e];
  }
}

// ---------- fused GATv2 edge phase: one wave per dst, online softmax, 4-edge unroll ----------
__device__ __forceinline__ float edge_dot(const float4 lv, const float4 rv, const float4 a) {
  float t, d = 0.f;
  t = lv.x + rv.x; t = t > 0.f ? t : NEG_ATT * t; d = fmaf(t, a.x, d);
  t = lv.y + rv.y; t = t > 0.f ? t : NEG_ATT * t; d = fmaf(t, a.y, d);
  t = lv.z + rv.z; t = t > 0.f ? t : NEG_ATT * t; d = fmaf(t, a.z, d);
  t = lv.w + rv.w; t = t > 0.f ? t : NEG_ATT * t; d = fmaf(t, a.w, d);
  d += __shfl_xor(d, 1);
  d += __shfl_xor(d, 2);
  d += __shfl_xor(d, 4);
  d += __shfl_xor(d, 8);
  return d;
}

__global__ __launch_bounds__(256) void gat_fused(
    const float* __restrict__ xl, const float* __restrict__ xr,
    const int* __restrict__ row_start, const int* __restrict__ csr_src,
    const float* __restrict__ att, const float* __restrict__ bo,
    float* __restrict__ outf, unsigned short* __restrict__ ohi,
    unsigned short* __restrict__ olo, int N, int split_out) {
  int dst = (blockIdx.x * 256 + threadIdx.x) >> 6;
  int lane = threadIdx.x & 63;
  if (dst >= N) return;
  int h = lane >> 4;
  int off = h * CH + (lane & 15) * 4;
  const float4 a = *(const float4*)&att[off];
  const float4 rv = *(const float4*)&xr[(size_t)dst * HC + off];
  float4 o = {0.f, 0.f, 0.f, 0.f};
  float m = -__builtin_inff();
  float s = 0.f;
  int p = row_start[dst];
  int end = row_start[dst + 1];
  for (; p + 4 <= end; p += 4) {
    int s0 = csr_src[p + 0], s1 = csr_src[p + 1];
    int s2 = csr_src[p + 2], s3 = csr_src[p + 3];
    const float4 lv0 = *(const float4*)&xl[(size_t)s0 * HC + off];
    const float4 lv1 = *(const float4*)&xl[(size_t)s1 * HC + off];
    const float4 lv2 = *(const float4*)&xl[(size_t)s2 * HC + off];
    const float4 lv3 = *(const float4*)&xl[(size_t)s3 * HC + off];
    float d0 = edge_dot(lv0, rv, a);
    float d1 = edge_dot(lv1, rv, a);
    float d2 = edge_dot(lv2, rv, a);
    float d3 = edge_dot(lv3, rv, a);
    float newm = fmaxf(fmaxf(fmaxf(d0, d1), fmaxf(d2, d3)), m);
    float sc = __expf(m - newm);
    float e0 = __expf(d0 - newm), e1 = __expf(d1 - newm);
    float e2 = __expf(d2 - newm), e3 = __expf(d3 - newm);
    s = fmaf(s, sc, (e0 + e1) + (e2 + e3));
    o.x = fmaf(o.x, sc, fmaf(e0, lv0.x, fmaf(e1, lv1.x, fmaf(e2, lv2.x, e3 * lv3.x))));
    o.y = fmaf(o.y, sc, fmaf(e0, lv0.y, fmaf(e1, lv1.y, fmaf(e2, lv2.y, e3 * lv3.y))));
    o.z = fmaf(o.z, sc, fmaf(e0, lv0.z, fmaf(e1, lv1.z, fmaf(e2, lv2.z, e3 * lv3.z))));
    o.w = fmaf(o.w, sc, fmaf(e0, lv0.w, fmaf(e1, lv1.w, fmaf(e2, lv2.w, e3 * lv3.w))));
    m = newm;
  }
  for (; p < end; p++) {
    int src = csr_src[p];
    const float4 lv = *(const float4*)&xl[(size_t)src * HC + off];
    float d = edge_dot(lv, rv, a);
    float newm = fmaxf(m, d);
    float sc = __expf(m - newm);
    float pe = __expf(d - newm);
    s = fmaf(s, sc, pe);
    o.x = fmaf(o.x, sc, pe * lv.x);
    o.y = fmaf(o.y, sc, pe * lv.y);
    o.z = fmaf(o.z, sc, pe * lv.z);
    o.w = fmaf(o.w, sc, pe * lv.w);
    m = newm;
  }
  float inv = 1.f / s;
  const float4 b4 = *(const float4*)&bo[off];
  float4 res;
  res.x = fmaf(o.x, inv, b4.x);
  res.y = fmaf(o.y, inv, b4.y);
  res.z = fmaf(o.z, inv, b4.z);
  res.w = fmaf(o.w, inv, b4.w);
  if (split_out) {
    // inter-layer LeakyReLU fused here, then split to bf16 hi/lo planes
    res.x = res.x > 0.f ? res.x : NEG_ACT * res.x;
    res.y = res.y > 0.f ? res.y : NEG_ACT * res.y;
    res.z = res.z > 0.f ? res.z : NEG_ACT * res.z;
    res.w = res.w > 0.f ? res.w : NEG_ACT * res.w;
    uint2 h2, l2;
    split2(res.x, res.y, h2.x, l2.x);
    split2(res.z, res.w, h2.y, l2.y);
    *(uint2*)&ohi[(size_t)dst * HC + off] = h2;
    *(uint2*)&olo[(size_t)dst * HC + off] = l2;
  } else {
    *(float4*)&outf[(size_t)dst * HC + off] = res;
  }
}

// ---------- pooling ----------
__global__ __launch_bounds__(256) void pool_partial(
    const float* __restrict__ h, const int* __restrict__ batch,
    float* __restrict__ out, int* __restrict__ cnt, int N) {
  __shared__ float part[NGRAPH][HC];
  __shared__ int bsh[256];
  __shared__ int cpart[NGRAPH];
  int j = threadIdx.x;
#pragma unroll
  for (int g = 0; g < NGRAPH; g++) part[g][j] = 0.f;
  if (j < NGRAPH) cpart[j] = 0;
  int n0 = blockIdx.x * 256;
  int nend = min(n0 + 256, N);
  int nj = n0 + j;
  bsh[j] = (nj < N) ? batch[nj] : 0;
  __syncthreads();
  if (nj < nend) atomicAdd(&cpart[bsh[j]], 1);
  for (int n = n0; n < nend; n++) {
    int g = bsh[n - n0];
    part[g][j] += h[(size_t)n * HC + j];
  }
  __syncthreads();
#pragma unroll
  for (int g = 0; g < NGRAPH; g++) {
    float v = part[g][j];
    if (v != 0.f) atomicAdd(&out[g * HC + j], v);
  }
  if (j < NGRAPH && cpart[j] > 0) atomicAdd(&cnt[j], cpart[j]);
}

__global__ __launch_bounds__(256) void pool_final(
    float* __restrict__ out, const int* __restrict__ cnt) {
  int g = blockIdx.x;
  int j = threadIdx.x;
  float c = (float)max(cnt[g], 1);
  out[g * HC + j] /= c;
}

extern "C" void kernel_launch(void* const* d_in, const int* in_sizes, int n_in,
                              void* d_out, int out_size, void* d_ws, size_t ws_size,
                              hipStream_t stream) {
  const float* x = (const float*)d_in[0];
  const int* ei = (const int*)d_in[1];
  const int* batch = (const int*)d_in[2];
  const int N = in_sizes[2];
  const int E = in_sizes[1] / 2;
  const int Etot = E + N;

  const float* Wl[3] = {(const float*)d_in[3], (const float*)d_in[9], (const float*)d_in[15]};
  const float* bl[3] = {(const float*)d_in[4], (const float*)d_in[10], (const float*)d_in[16]};
  const float* Wr[3] = {(const float*)d_in[5], (const float*)d_in[11], (const float*)d_in[17]};
  const float* br[3] = {(const float*)d_in[6], (const float*)d_in[12], (const float*)d_in[18]};
  const float* att[3] = {(const float*)d_in[7], (const float*)d_in[13], (const float*)d_in[19]};
  const float* bo[3] = {(const float*)d_in[8], (const float*)d_in[14], (const float*)d_in[20]};

  // ws layout
  float* B0 = (float*)d_ws;                 // planes region (layers 1-2) / fp32 h3 (layer 3)
  float* B1 = B0 + (size_t)N * HC;          // xl
  float* B2 = B1 + (size_t)N * HC;          // xr
  unsigned short* w1hi = (unsigned short*)(B2 + (size_t)N * HC);
  unsigned short* w1lo = w1hi + 512 * 128;
  unsigned short* w2hi = w1lo + 512 * 128;
  unsigned short* w2lo = w2hi + 512 * 256;
  unsigned short* w3hi = w2lo + 512 * 256;
  unsigned short* w3lo = w3hi + 512 * 256;
  int* counts = (int*)(w3lo + 512 * 256);
  int* row_start = counts + N;              // N+1
  int* bsum = row_start + N + 1;            // 64
  int* fill_pos = bsum + 64;                // N
  int* csr_src = fill_pos + N;              // Etot
  int* cnt = csr_src + Etot;                // NGRAPH

  // plane views inside B0
  unsigned short* xhiL1 = (unsigned short*)B0;
  unsigned short* xloL1 = xhiL1 + (size_t)N * 128;   // layer-1 input planes (K=128)
  unsigned short* xhiL = (unsigned short*)B0;
  unsigned short* xloL = xhiL + (size_t)N * HC;      // layer-2/3 input planes (K=256)

  const int* esrc = ei;
  const int* edst = ei + E;

  // ---- conversions ----
  convert_x<<<(N * 128 / 4 + 255) / 256, 256, 0, stream>>>(x, xhiL1, xloL1, N * 128 / 4);
  convert_w<<<512 * 128 / 1024, 256, 0, stream>>>(Wl[0], Wr[0], w1hi, w1lo, 128);
  convert_w<<<512 * 256 / 1024, 256, 0, stream>>>(Wl[1], Wr[1], w2hi, w2lo, 256);
  convert_w<<<512 * 256 / 1024, 256, 0, stream>>>(Wl[2], Wr[2], w3hi, w3lo, 256);

  // ---- CSR build ----
  const int nscan = (N + 1023) / 1024;  // 49 (<=64 required by scan_tops)
  set_ones<<<(N + 255) / 256, 256, 0, stream>>>(counts, N);
  hist_dst<<<(E + 255) / 256, 256, 0, stream>>>(edst, counts, E);
  scan_blocks<<<nscan, 256, 0, stream>>>(counts, row_start, bsum, N);
  scan_tops<<<1, 64, 0, stream>>>(bsum, nscan);
  scan_add<<<nscan - 1, 256, 0, stream>>>(row_start, bsum, N);
  csr_init<<<(N + 255) / 256, 256, 0, stream>>>(row_start, fill_pos, csr_src, N);
  csr_scatter<<<(E + 255) / 256, 256, 0, stream>>>(esrc, edst, fill_pos, csr_src, E);

  const dim3 ggrid(4, (N + 127) / 128);  // col-blocks fastest: A-tile L2 reuse
  const int fblocks = (N * 64 + 255) / 256;

  // layer 1 (K=128)
  gemm_fused<<<ggrid, 256, 0, stream>>>(xhiL1, xloL1, w1hi, w1lo, bl[0], br[0], B1, B2, N, 128);
  gat_fused<<<fblocks, 256, 0, stream>>>(B1, B2, row_start, csr_src, att[0], bo[0],
                                         nullptr, xhiL, xloL, N, 1);
  // layer 2 (K=256)
  gemm_fused<<<ggrid, 256, 0, stream>>>(xhiL, xloL, w2hi, w2lo, bl[1], br[1], B1, B2, N, 256);
  gat_fused<<<fblocks, 256, 0, stream>>>(B1, B2, row_start, csr_src, att[1], bo[1],
                                         nullptr, xhiL, xloL, N, 1);
  // layer 3 (K=256), fp32 out for pooling
  gemm_fused<<<ggrid, 256, 0, stream>>>(xhiL, xloL, w3hi, w3lo, bl[2], br[2], B1, B2, N, 256);
  gat_fused<<<fblocks, 256, 0, stream>>>(B1, B2, row_start, csr_src, att[2], bo[2],
                                         B0, nullptr, nullptr, N, 0);

  (void)hipMemsetAsync(d_out, 0, NGRAPH * HC * sizeof(float), stream);
  (void)hipMemsetAsync(cnt, 0, NGRAPH * sizeof(int), stream);
  pool_partial<<<(N + 255) / 256, 256, 0, stream>>>(B0, batch, (float*)d_out, cnt, N);
  pool_final<<<NGRAPH, 256, 0, stream>>>((float*)d_out, cnt);
}

// Round 5
// 748.080 us; speedup vs baseline: 13.7455x; 1.1939x over previous
//
#include <hip/hip_runtime.h>

#define HEADS 4
#define CH 64
#define HC 256
#define NGRAPH 32
#define NEG_ATT 0.2f
#define NEG_ACT 0.01f

typedef __attribute__((ext_vector_type(8))) short bf16x8;
typedef __attribute__((ext_vector_type(4))) float f32x4;

// split two fp32 into packed hi-bf16 pair and lo-bf16 pair (truncation; lo captures residual)
__device__ __forceinline__ void split2(float a, float b, unsigned& hi, unsigned& lo) {
  unsigned ua = __float_as_uint(a), ub = __float_as_uint(b);
  float la = a - __uint_as_float(ua & 0xFFFF0000u);
  float lb = b - __uint_as_float(ub & 0xFFFF0000u);
  hi = __builtin_amdgcn_perm(ub, ua, 0x07060302u);  // [hi16(b) : hi16(a)]
  lo = __builtin_amdgcn_perm(__float_as_uint(lb), __float_as_uint(la), 0x07060302u);
}

// round-to-nearest-even fp32 -> bf16 (returned in low 16 bits)
__device__ __forceinline__ unsigned rtn_bf16(float f) {
  unsigned u = __float_as_uint(f);
  return (u + 0x7FFFu + ((u >> 16) & 1u)) >> 16;
}

// ---------- one-time conversions to split-bf16 planes ----------
__global__ __launch_bounds__(256) void convert_x(
    const float* __restrict__ X, unsigned short* __restrict__ xhi,
    unsigned short* __restrict__ xlo, int total4) {
  int g = blockIdx.x * 256 + threadIdx.x;
  if (g >= total4) return;
  float4 v = *(const float4*)&X[(size_t)g * 4];
  uint2 h2, l2;
  split2(v.x, v.y, h2.x, l2.x);
  split2(v.z, v.w, h2.y, l2.y);
  *(uint2*)&xhi[(size_t)g * 4] = h2;
  *(uint2*)&xlo[(size_t)g * 4] = l2;
}

// W' = [Wl; Wr] (512 x K) -> hi/lo planes
__global__ __launch_bounds__(256) void convert_w(
    const float* __restrict__ Wl, const float* __restrict__ Wr,
    unsigned short* __restrict__ whi, unsigned short* __restrict__ wlo, int K) {
  int g = blockIdx.x * 256 + threadIdx.x;  // 512*K/4 threads
  int e4 = g * 4;
  int half = 256 * K;
  const float* src = (e4 < half) ? &Wl[e4] : &Wr[e4 - half];
  float4 v = *(const float4*)src;
  uint2 h2, l2;
  split2(v.x, v.y, h2.x, l2.x);
  split2(v.z, v.w, h2.y, l2.y);
  *(uint2*)&whi[(size_t)e4] = h2;
  *(uint2*)&wlo[(size_t)e4] = l2;
}

// ---------- fused MFMA GEMM: [xl(bf16) | xr(fp32)] = X(hi/lo) @ W'(hi/lo)^T + bias ----------
__global__ __launch_bounds__(256) void gemm_fused(
    const unsigned short* __restrict__ xhi, const unsigned short* __restrict__ xlo,
    const unsigned short* __restrict__ whi, const unsigned short* __restrict__ wlo,
    const float* __restrict__ bl, const float* __restrict__ br,
    unsigned short* __restrict__ Y1, float* __restrict__ Y2, int N, int K) {
  __shared__ unsigned short Ahi[128][32];
  __shared__ unsigned short Alo[128][32];
  __shared__ unsigned short Bhi[128][32];
  __shared__ unsigned short Blo[128][32];

  const int tid = threadIdx.x;
  const int wave = tid >> 6;
  const int lane = tid & 63;
  const int quad = lane >> 4;
  const int l16 = lane & 15;
  const int wr = (wave >> 1) * 64;
  const int wc = (wave & 1) * 64;
  const int col0 = blockIdx.x * 128;  // grid.x = 4 -> cols 0..511 of W'
  const int row0 = blockIdx.y * 128;

  f32x4 acc[4][4];
#pragma unroll
  for (int i = 0; i < 4; i++)
#pragma unroll
    for (int j = 0; j < 4; j++) acc[i][j] = (f32x4){0.f, 0.f, 0.f, 0.f};

  const int r_s = tid >> 2;       // 0..63
  const int c_s = (tid & 3) * 8;  // ushort offset of 16B chunk

  for (int k0 = 0; k0 < K; k0 += 32) {
#pragma unroll
    for (int it = 0; it < 2; it++) {
      int r = r_s + it * 64;
      int gr = row0 + r;
      if (gr >= N) gr = N - 1;
      size_t ga = (size_t)gr * K + k0 + c_s;
      *(uint4*)&Ahi[r][c_s] = *(const uint4*)&xhi[ga];
      *(uint4*)&Alo[r][c_s] = *(const uint4*)&xlo[ga];
      size_t gb = (size_t)(col0 + r) * K + k0 + c_s;
      *(uint4*)&Bhi[r][c_s] = *(const uint4*)&whi[gb];
      *(uint4*)&Blo[r][c_s] = *(const uint4*)&wlo[gb];
    }
    __syncthreads();

    bf16x8 ahi[4], alo[4], bhi[4], blo[4];
#pragma unroll
    for (int i = 0; i < 4; i++) {
      ahi[i] = *(const bf16x8*)&Ahi[wr + i * 16 + l16][quad * 8];
      alo[i] = *(const bf16x8*)&Alo[wr + i * 16 + l16][quad * 8];
      bhi[i] = *(const bf16x8*)&Bhi[wc + i * 16 + l16][quad * 8];
      blo[i] = *(const bf16x8*)&Blo[wc + i * 16 + l16][quad * 8];
    }
#pragma unroll
    for (int i = 0; i < 4; i++)
#pragma unroll
      for (int j = 0; j < 4; j++) {
        acc[i][j] = __builtin_amdgcn_mfma_f32_16x16x32_bf16(ahi[i], bhi[j], acc[i][j], 0, 0, 0);
        acc[i][j] = __builtin_amdgcn_mfma_f32_16x16x32_bf16(ahi[i], blo[j], acc[i][j], 0, 0, 0);
        acc[i][j] = __builtin_amdgcn_mfma_f32_16x16x32_bf16(alo[i], bhi[j], acc[i][j], 0, 0, 0);
      }
    __syncthreads();
  }

  // epilogue: D row = quad*4+reg, col = l16; xl -> bf16 (RTN), xr -> fp32
#pragma unroll
  for (int j = 0; j < 4; j++) {
    int colg = col0 + wc + j * 16 + l16;  // 0..511
    if (colg < HC) {
      float bv = bl[colg];
#pragma unroll
      for (int i = 0; i < 4; i++)
#pragma unroll
        for (int r = 0; r < 4; r++) {
          int row = row0 + wr + i * 16 + quad * 4 + r;
          if (row < N)
            Y1[(size_t)row * HC + colg] = (unsigned short)rtn_bf16(acc[i][j][r] + bv);
        }
    } else {
      int cc = colg - HC;
      float bv = br[cc];
#pragma unroll
      for (int i = 0; i < 4; i++)
#pragma unroll
        for (int r = 0; r < 4; r++) {
          int row = row0 + wr + i * 16 + quad * 4 + r;
          if (row < N) Y2[(size_t)row * HC + cc] = acc[i][j][r] + bv;
        }
    }
  }
}

// ---------- CSR build ----------
__global__ __launch_bounds__(256) void hist_dst(
    const int* __restrict__ edst, int* __restrict__ counts, int E) {
  int e = blockIdx.x * 256 + threadIdx.x;
  if (e < E) atomicAdd(&counts[edst[e]], 1);
}

// hierarchical scan over (counts[i]+1): per-1024-chunk scan -> 1-wave top scan -> add
__global__ __launch_bounds__(256) void scan_blocks(
    const int* __restrict__ counts, int* __restrict__ row_start,
    int* __restrict__ bsum, int N) {
  __shared__ int tmp[256];
  int t = threadIdx.x;
  int base = blockIdx.x * 1024 + t * 4;
  int v0 = (base     < N) ? counts[base]     + 1 : 0;
  int v1 = (base + 1 < N) ? counts[base + 1] + 1 : 0;
  int v2 = (base + 2 < N) ? counts[base + 2] + 1 : 0;
  int v3 = (base + 3 < N) ? counts[base + 3] + 1 : 0;
  int c1 = v0 + v1, c2 = c1 + v2, tot = c2 + v3;
  tmp[t] = tot;
  __syncthreads();
  for (int off = 1; off < 256; off <<= 1) {
    int add = (t >= off) ? tmp[t - off] : 0;
    __syncthreads();
    tmp[t] += add;
    __syncthreads();
  }
  int excl = tmp[t] - tot;
  if (base     < N) row_start[base + 1] = excl + v0;
  if (base + 1 < N) row_start[base + 2] = excl + c1;
  if (base + 2 < N) row_start[base + 3] = excl + c2;
  if (base + 3 < N) row_start[base + 4] = excl + tot;
  if (t == 255) bsum[blockIdx.x] = tmp[255];
  if (blockIdx.x == 0 && t == 0) row_start[0] = 0;
}

__global__ void scan_tops(int* __restrict__ bsum, int nb) {
  int lane = threadIdx.x;  // 64 threads, 1 block; nb <= 64
  int v = (lane < nb) ? bsum[lane] : 0;
  for (int off = 1; off < 64; off <<= 1) {
    int u = __shfl_up(v, off);
    if (lane >= off) v += u;
  }
  if (lane < nb) bsum[lane] = v;  // inclusive
}

__global__ __launch_bounds__(256) void scan_add(
    int* __restrict__ row_start, const int* __restrict__ bsum, int N) {
  int off = bsum[blockIdx.x];
  int i = (blockIdx.x + 1) * 1024 + threadIdx.x * 4;
#pragma unroll
  for (int k = 0; k < 4; k++)
    if (i + k < N) row_start[i + k + 1] += off;
}

__global__ __launch_bounds__(256) void csr_init(
    const int* __restrict__ row_start, int* __restrict__ fill_pos,
    int* __restrict__ csr_src, int N) {
  int i = blockIdx.x * 256 + threadIdx.x;
  if (i < N) {
    int p = row_start[i];
    csr_src[p] = i;  // self-loop first
    fill_pos[i] = p + 1;
  }
}

__global__ __launch_bounds__(256) void csr_scatter(
    const int* __restrict__ esrc, const int* __restrict__ edst,
    int* __restrict__ fill_pos, int* __restrict__ csr_src, int E) {
  int e = blockIdx.x * 256 + threadIdx.x;
  if (e < E) {
    int p = atomicAdd(&fill_pos[edst[e]], 1);
    csr_src[p] = esrc[e];
  }
}

// ---------- fused GATv2 edge phase: one wave per dst, online softmax, bf16 xl gather ----------
__device__ __forceinline__ float4 unpack_bf16x4(uint2 q) {
  float4 r;
  r.x = __uint_as_float(q.x << 16);
  r.y = __uint_as_float(q.x & 0xFFFF0000u);
  r.z = __uint_as_float(q.y << 16);
  r.w = __uint_as_float(q.y & 0xFFFF0000u);
  return r;
}

__device__ __forceinline__ float edge_dot(const float4 lv, const float4 rv, const float4 a) {
  float t, d = 0.f;
  t = lv.x + rv.x; t = t > 0.f ? t : NEG_ATT * t; d = fmaf(t, a.x, d);
  t = lv.y + rv.y; t = t > 0.f ? t : NEG_ATT * t; d = fmaf(t, a.y, d);
  t = lv.z + rv.z; t = t > 0.f ? t : NEG_ATT * t; d = fmaf(t, a.z, d);
  t = lv.w + rv.w; t = t > 0.f ? t : NEG_ATT * t; d = fmaf(t, a.w, d);
  d += __shfl_xor(d, 1);
  d += __shfl_xor(d, 2);
  d += __shfl_xor(d, 4);
  d += __shfl_xor(d, 8);
  return d;
}

__global__ __launch_bounds__(256) void gat_fused(
    const unsigned short* __restrict__ xl, const float* __restrict__ xr,
    const int* __restrict__ row_start, const int* __restrict__ csr_src,
    const float* __restrict__ att, const float* __restrict__ bo,
    float* __restrict__ outf, unsigned short* __restrict__ ohi,
    unsigned short* __restrict__ olo, int N, int split_out) {
  int dst = (blockIdx.x * 256 + threadIdx.x) >> 6;
  int lane = threadIdx.x & 63;
  if (dst >= N) return;
  int h = lane >> 4;
  int off = h * CH + (lane & 15) * 4;
  const float4 a = *(const float4*)&att[off];
  const float4 rv = *(const float4*)&xr[(size_t)dst * HC + off];
  float4 o = {0.f, 0.f, 0.f, 0.f};
  float m = -__builtin_inff();
  float s = 0.f;
  int p = row_start[dst];
  int end = row_start[dst + 1];
  for (; p + 4 <= end; p += 4) {
    int s0 = csr_src[p + 0], s1 = csr_src[p + 1];
    int s2 = csr_src[p + 2], s3 = csr_src[p + 3];
    const float4 lv0 = unpack_bf16x4(*(const uint2*)&xl[(size_t)s0 * HC + off]);
    const float4 lv1 = unpack_bf16x4(*(const uint2*)&xl[(size_t)s1 * HC + off]);
    const float4 lv2 = unpack_bf16x4(*(const uint2*)&xl[(size_t)s2 * HC + off]);
    const float4 lv3 = unpack_bf16x4(*(const uint2*)&xl[(size_t)s3 * HC + off]);
    float d0 = edge_dot(lv0, rv, a);
    float d1 = edge_dot(lv1, rv, a);
    float d2 = edge_dot(lv2, rv, a);
    float d3 = edge_dot(lv3, rv, a);
    float newm = fmaxf(fmaxf(fmaxf(d0, d1), fmaxf(d2, d3)), m);
    float sc = __expf(m - newm);
    float e0 = __expf(d0 - newm), e1 = __expf(d1 - newm);
    float e2 = __expf(d2 - newm), e3 = __expf(d3 - newm);
    s = fmaf(s, sc, (e0 + e1) + (e2 + e3));
    o.x = fmaf(o.x, sc, fmaf(e0, lv0.x, fmaf(e1, lv1.x, fmaf(e2, lv2.x, e3 * lv3.x))));
    o.y = fmaf(o.y, sc, fmaf(e0, lv0.y, fmaf(e1, lv1.y, fmaf(e2, lv2.y, e3 * lv3.y))));
    o.z = fmaf(o.z, sc, fmaf(e0, lv0.z, fmaf(e1, lv1.z, fmaf(e2, lv2.z, e3 * lv3.z))));
    o.w = fmaf(o.w, sc, fmaf(e0, lv0.w, fmaf(e1, lv1.w, fmaf(e2, lv2.w, e3 * lv3.w))));
    m = newm;
  }
  for (; p < end; p++) {
    int src = csr_src[p];
    const float4 lv = unpack_bf16x4(*(const uint2*)&xl[(size_t)src * HC + off]);
    float d = edge_dot(lv, rv, a);
    float newm = fmaxf(m, d);
    float sc = __expf(m - newm);
    float pe = __expf(d - newm);
    s = fmaf(s, sc, pe);
    o.x = fmaf(o.x, sc, pe * lv.x);
    o.y = fmaf(o.y, sc, pe * lv.y);
    o.z = fmaf(o.z, sc, pe * lv.z);
    o.w = fmaf(o.w, sc, pe * lv.w);
    m = newm;
  }
  float inv = 1.f / s;
  const float4 b4 = *(const float4*)&bo[off];
  float4 res;
  res.x = fmaf(o.x, inv, b4.x);
  res.y = fmaf(o.y, inv, b4.y);
  res.z = fmaf(o.z, inv, b4.z);
  res.w = fmaf(o.w, inv, b4.w);
  if (split_out) {
    res.x = res.x > 0.f ? res.x : NEG_ACT * res.x;
    res.y = res.y > 0.f ? res.y : NEG_ACT * res.y;
    res.z = res.z > 0.f ? res.z : NEG_ACT * res.z;
    res.w = res.w > 0.f ? res.w : NEG_ACT * res.w;
    uint2 h2, l2;
    split2(res.x, res.y, h2.x, l2.x);
    split2(res.z, res.w, h2.y, l2.y);
    *(uint2*)&ohi[(size_t)dst * HC + off] = h2;
    *(uint2*)&olo[(size_t)dst * HC + off] = l2;
  } else {
    *(float4*)&outf[(size_t)dst * HC + off] = res;
  }
}

// ---------- pooling ----------
__global__ __launch_bounds__(256) void pool_partial(
    const float* __restrict__ h, const int* __restrict__ batch,
    float* __restrict__ out, int* __restrict__ cnt, int N) {
  __shared__ float part[NGRAPH][HC];
  __shared__ int bsh[256];
  __shared__ int cpart[NGRAPH];
  int j = threadIdx.x;
#pragma unroll
  for (int g = 0; g < NGRAPH; g++) part[g][j] = 0.f;
  if (j < NGRAPH) cpart[j] = 0;
  int n0 = blockIdx.x * 256;
  int nend = min(n0 + 256, N);
  int nj = n0 + j;
  bsh[j] = (nj < N) ? batch[nj] : 0;
  __syncthreads();
  if (nj < nend) atomicAdd(&cpart[bsh[j]], 1);
  for (int n = n0; n < nend; n++) {
    int g = bsh[n - n0];
    part[g][j] += h[(size_t)n * HC + j];
  }
  __syncthreads();
#pragma unroll
  for (int g = 0; g < NGRAPH; g++) {
    float v = part[g][j];
    if (v != 0.f) atomicAdd(&out[g * HC + j], v);
  }
  if (j < NGRAPH && cpart[j] > 0) atomicAdd(&cnt[j], cpart[j]);
}

__global__ __launch_bounds__(256) void pool_final(
    float* __restrict__ out, const int* __restrict__ cnt) {
  int g = blockIdx.x;
  int j = threadIdx.x;
  float c = (float)max(cnt[g], 1);
  out[g * HC + j] /= c;
}

extern "C" void kernel_launch(void* const* d_in, const int* in_sizes, int n_in,
                              void* d_out, int out_size, void* d_ws, size_t ws_size,
                              hipStream_t stream) {
  const float* x = (const float*)d_in[0];
  const int* ei = (const int*)d_in[1];
  const int* batch = (const int*)d_in[2];
  const int N = in_sizes[2];
  const int E = in_sizes[1] / 2;
  const int Etot = E + N;

  const float* Wl[3] = {(const float*)d_in[3], (const float*)d_in[9], (const float*)d_in[15]};
  const float* bl[3] = {(const float*)d_in[4], (const float*)d_in[10], (const float*)d_in[16]};
  const float* Wr[3] = {(const float*)d_in[5], (const float*)d_in[11], (const float*)d_in[17]};
  const float* br[3] = {(const float*)d_in[6], (const float*)d_in[12], (const float*)d_in[18]};
  const float* att[3] = {(const float*)d_in[7], (const float*)d_in[13], (const float*)d_in[19]};
  const float* bo[3] = {(const float*)d_in[8], (const float*)d_in[14], (const float*)d_in[20]};

  // ws layout
  float* B0 = (float*)d_ws;                 // planes region (layers 1-2) / fp32 h3 (layer 3)
  float* B1 = B0 + (size_t)N * HC;          // xl (bf16, uses half the slot)
  float* B2 = B1 + (size_t)N * HC;          // xr (fp32)
  unsigned short* w1hi = (unsigned short*)(B2 + (size_t)N * HC);
  unsigned short* w1lo = w1hi + 512 * 128;
  unsigned short* w2hi = w1lo + 512 * 128;
  unsigned short* w2lo = w2hi + 512 * 256;
  unsigned short* w3hi = w2lo + 512 * 256;
  unsigned short* w3lo = w3hi + 512 * 256;
  int* counts = (int*)(w3lo + 512 * 256);
  int* row_start = counts + N;              // N+1
  int* bsum = row_start + N + 1;            // 64
  int* fill_pos = bsum + 64;                // N
  int* csr_src = fill_pos + N;              // Etot
  int* cnt = csr_src + Etot;                // NGRAPH

  unsigned short* xlB = (unsigned short*)B1;

  // plane views inside B0
  unsigned short* xhiL1 = (unsigned short*)B0;
  unsigned short* xloL1 = xhiL1 + (size_t)N * 128;   // layer-1 input planes (K=128)
  unsigned short* xhiL = (unsigned short*)B0;
  unsigned short* xloL = xhiL + (size_t)N * HC;      // layer-2/3 input planes (K=256)

  const int* esrc = ei;
  const int* edst = ei + E;

  // ---- conversions ----
  convert_x<<<(N * 128 / 4 + 255) / 256, 256, 0, stream>>>(x, xhiL1, xloL1, N * 128 / 4);
  convert_w<<<512 * 128 / 1024, 256, 0, stream>>>(Wl[0], Wr[0], w1hi, w1lo, 128);
  convert_w<<<512 * 256 / 1024, 256, 0, stream>>>(Wl[1], Wr[1], w2hi, w2lo, 256);
  convert_w<<<512 * 256 / 1024, 256, 0, stream>>>(Wl[2], Wr[2], w3hi, w3lo, 256);

  // ---- CSR build ----
  const int nscan = (N + 1023) / 1024;  // 49 (<=64 required by scan_tops)
  (void)hipMemsetAsync(counts, 0, (size_t)N * sizeof(int), stream);
  hist_dst<<<(E + 255) / 256, 256, 0, stream>>>(edst, counts, E);
  scan_blocks<<<nscan, 256, 0, stream>>>(counts, row_start, bsum, N);
  scan_tops<<<1, 64, 0, stream>>>(bsum, nscan);
  scan_add<<<nscan - 1, 256, 0, stream>>>(row_start, bsum, N);
  csr_init<<<(N + 255) / 256, 256, 0, stream>>>(row_start, fill_pos, csr_src, N);
  csr_scatter<<<(E + 255) / 256, 256, 0, stream>>>(esrc, edst, fill_pos, csr_src, E);

  const dim3 ggrid(4, (N + 127) / 128);
  const int fblocks = (N * 64 + 255) / 256;

  // layer 1 (K=128)
  gemm_fused<<<ggrid, 256, 0, stream>>>(xhiL1, xloL1, w1hi, w1lo, bl[0], br[0], xlB, B2, N, 128);
  gat_fused<<<fblocks, 256, 0, stream>>>(xlB, B2, row_start, csr_src, att[0], bo[0],
                                         nullptr, xhiL, xloL, N, 1);
  // layer 2 (K=256)
  gemm_fused<<<ggrid, 256, 0, stream>>>(xhiL, xloL, w2hi, w2lo, bl[1], br[1], xlB, B2, N, 256);
  gat_fused<<<fblocks, 256, 0, stream>>>(xlB, B2, row_start, csr_src, att[1], bo[1],
                                         nullptr, xhiL, xloL, N, 1);
  // layer 3 (K=256), fp32 out for pooling
  gemm_fused<<<ggrid, 256, 0, stream>>>(xhiL, xloL, w3hi, w3lo, bl[2], br[2], xlB, B2, N, 256);
  gat_fused<<<fblocks, 256, 0, stream>>>(xlB, B2, row_start, csr_src, att[2], bo[2],
                                         B0, nullptr, nullptr, N, 0);

  (void)hipMemsetAsync(d_out, 0, NGRAPH * HC * sizeof(float), stream);
  (void)hipMemsetAsync(cnt, 0, NGRAPH * sizeof(int), stream);
  pool_partial<<<(N + 255) / 256, 256, 0, stream>>>(B0, batch, (float*)d_out, cnt, N);
  pool_final<<<NGRAPH, 256, 0, stream>>>((float*)d_out, cnt);
}

// Round 6
// 696.235 us; speedup vs baseline: 14.7690x; 1.0745x over previous
//
#include <hip/hip_runtime.h>

#define HEADS 4
#define CH 64
#define HC 256
#define NGRAPH 32
#define NEG_ATT 0.2f
#define NEG_ACT 0.01f

typedef __attribute__((ext_vector_type(8))) short bf16x8;
typedef __attribute__((ext_vector_type(4))) float f32x4;

typedef __attribute__((address_space(3))) unsigned int lds_u32;
typedef const __attribute__((address_space(1))) unsigned int glob_u32;

// async global->LDS, 16B per lane; LDS dest = wave-uniform base + lane*16
__device__ __forceinline__ void gl_lds16(const void* g, void* l) {
  __builtin_amdgcn_global_load_lds((glob_u32*)(uintptr_t)g,
                                   (lds_u32*)(unsigned int)(uintptr_t)l, 16, 0, 0);
}

// split two fp32 into packed hi-bf16 pair and lo-bf16 pair (truncation; lo captures residual)
__device__ __forceinline__ void split2(float a, float b, unsigned& hi, unsigned& lo) {
  unsigned ua = __float_as_uint(a), ub = __float_as_uint(b);
  float la = a - __uint_as_float(ua & 0xFFFF0000u);
  float lb = b - __uint_as_float(ub & 0xFFFF0000u);
  hi = __builtin_amdgcn_perm(ub, ua, 0x07060302u);  // [hi16(b) : hi16(a)]
  lo = __builtin_amdgcn_perm(__float_as_uint(lb), __float_as_uint(la), 0x07060302u);
}

// round-to-nearest-even fp32 -> bf16 (low 16 bits)
__device__ __forceinline__ unsigned rtn_bf16(float f) {
  unsigned u = __float_as_uint(f);
  return (u + 0x7FFFu + ((u >> 16) & 1u)) >> 16;
}

// ---------- conversions ----------
__global__ __launch_bounds__(256) void convert_x(
    const float* __restrict__ X, unsigned short* __restrict__ xhi,
    unsigned short* __restrict__ xlo, int total4) {
  int g = blockIdx.x * 256 + threadIdx.x;
  if (g >= total4) return;
  float4 v = *(const float4*)&X[(size_t)g * 4];
  uint2 h2, l2;
  split2(v.x, v.y, h2.x, l2.x);
  split2(v.z, v.w, h2.y, l2.y);
  *(uint2*)&xhi[(size_t)g * 4] = h2;
  *(uint2*)&xlo[(size_t)g * 4] = l2;
}

// W' = [Wl; Wr] (512 x K) -> MFMA-fragment-ordered hi/lo planes.
// chunk ci = (kb*32 + ct)*64 + lane holds W'[ct*16 + (lane&15)][kb*32 + (lane>>4)*8 .. +8]
__global__ __launch_bounds__(256) void convert_w_frag(
    const float* __restrict__ Wl, const float* __restrict__ Wr,
    unsigned short* __restrict__ wfhi, unsigned short* __restrict__ wflo, int K) {
  int g = blockIdx.x * 256 + threadIdx.x;  // K*64 chunks
  int lane = g & 63;
  int ct = (g >> 6) & 31;
  int kb = g >> 11;
  int col = ct * 16 + (lane & 15);
  int k = kb * 32 + (lane >> 4) * 8;
  const float* src = (col < HC) ? &Wl[(size_t)col * K + k] : &Wr[(size_t)(col - HC) * K + k];
  float4 v0 = *(const float4*)src;
  float4 v1 = *(const float4*)(src + 4);
  uint4 hq, lq;
  split2(v0.x, v0.y, hq.x, lq.x);
  split2(v0.z, v0.w, hq.y, lq.y);
  split2(v1.x, v1.y, hq.z, lq.z);
  split2(v1.z, v1.w, hq.w, lq.w);
  *(uint4*)&wfhi[(size_t)g * 8] = hq;
  *(uint4*)&wflo[(size_t)g * 8] = lq;
}

// ---------- MFMA GEMM: [xl(bf16) | xr(fp32)] = X(hi/lo) @ W'(hi/lo)^T + bias ----------
// 128 rows x 128 cols per block, 4 waves. A: double-buffered LDS via global_load_lds.
// B: fragment-ordered global loads (L2-resident). 3-term split-bf16 MFMA.
__global__ __launch_bounds__(256) void gemm_fused(
    const unsigned short* __restrict__ xhi, const unsigned short* __restrict__ xlo,
    const unsigned short* __restrict__ wfhi, const unsigned short* __restrict__ wflo,
    const float* __restrict__ bl, const float* __restrict__ br,
    unsigned short* __restrict__ Y1, float* __restrict__ Y2, int N, int K) {
  __shared__ unsigned short Ah[2][128][32];
  __shared__ unsigned short Al[2][128][32];

  const int tid = threadIdx.x;
  const int wave = tid >> 6;
  const int lane = tid & 63;
  const int quad = lane >> 4;
  const int l16 = lane & 15;
  const int wr = (wave >> 1) * 64;
  const int wc = (wave & 1) * 64;
  const int col0 = blockIdx.x * 128;
  const int row0 = blockIdx.y * 128;
  const int ctg0 = blockIdx.x * 8 + (wave & 1) * 4;  // wave's first col-tile (global)
  const int nkb = K >> 5;

  // staging addresses for this thread (2 chunks per plane)
  const int c0 = tid, c1 = tid + 256;
  const int r0g = row0 + (c0 >> 2), r1g = row0 + (c1 >> 2);
  const int ko0 = (c0 & 3) * 8, ko1 = (c1 & 3) * 8;
  const int gr0 = (r0g < N) ? r0g : N - 1;
  const int gr1 = (r1g < N) ? r1g : N - 1;

  f32x4 acc[4][4];
#pragma unroll
  for (int i = 0; i < 4; i++)
#pragma unroll
    for (int j = 0; j < 4; j++) acc[i][j] = (f32x4){0.f, 0.f, 0.f, 0.f};

  // prologue: stage k-tile 0 into buffer 0
  {
    size_t ga0 = (size_t)gr0 * K + ko0;
    size_t ga1 = (size_t)gr1 * K + ko1;
    gl_lds16(&xhi[ga0], &Ah[0][c0 >> 2][ko0]);
    gl_lds16(&xlo[ga0], &Al[0][c0 >> 2][ko0]);
    gl_lds16(&xhi[ga1], &Ah[0][c1 >> 2][ko1]);
    gl_lds16(&xlo[ga1], &Al[0][c1 >> 2][ko1]);
  }

  int p = 0;
  for (int kb = 0; kb < nkb; kb++) {
    // B fragments for this k-tile (global, L2-resident, coalesced 16B/lane)
    bf16x8 bhi[4], blo[4];
#pragma unroll
    for (int j = 0; j < 4; j++) {
      size_t ci = ((size_t)kb * 32 + ctg0 + j) * 64 + lane;
      bhi[j] = *(const bf16x8*)&wfhi[ci * 8];
      blo[j] = *(const bf16x8*)&wflo[ci * 8];
    }
    __syncthreads();  // buffer p staged (vmcnt drain) + prior reads of p^1 done
    if (kb + 1 < nkb) {
      int k0 = (kb + 1) * 32;
      size_t ga0 = (size_t)gr0 * K + k0 + ko0;
      size_t ga1 = (size_t)gr1 * K + k0 + ko1;
      int q = p ^ 1;
      gl_lds16(&xhi[ga0], &Ah[q][c0 >> 2][ko0]);
      gl_lds16(&xlo[ga0], &Al[q][c0 >> 2][ko0]);
      gl_lds16(&xhi[ga1], &Ah[q][c1 >> 2][ko1]);
      gl_lds16(&xlo[ga1], &Al[q][c1 >> 2][ko1]);
    }
    bf16x8 ahi[4], alo[4];
#pragma unroll
    for (int i = 0; i < 4; i++) {
      ahi[i] = *(const bf16x8*)&Ah[p][wr + i * 16 + l16][quad * 8];
      alo[i] = *(const bf16x8*)&Al[p][wr + i * 16 + l16][quad * 8];
    }
#pragma unroll
    for (int i = 0; i < 4; i++)
#pragma unroll
      for (int j = 0; j < 4; j++) {
        acc[i][j] = __builtin_amdgcn_mfma_f32_16x16x32_bf16(ahi[i], bhi[j], acc[i][j], 0, 0, 0);
        acc[i][j] = __builtin_amdgcn_mfma_f32_16x16x32_bf16(ahi[i], blo[j], acc[i][j], 0, 0, 0);
        acc[i][j] = __builtin_amdgcn_mfma_f32_16x16x32_bf16(alo[i], bhi[j], acc[i][j], 0, 0, 0);
      }
    p ^= 1;
  }

  // epilogue: D row = quad*4+reg, col = l16; xl -> bf16 (RTN), xr -> fp32
#pragma unroll
  for (int j = 0; j < 4; j++) {
    int colg = col0 + wc + j * 16 + l16;  // 0..511
    if (colg < HC) {
      float bv = bl[colg];
#pragma unroll
      for (int i = 0; i < 4; i++)
#pragma unroll
        for (int r = 0; r < 4; r++) {
          int row = row0 + wr + i * 16 + quad * 4 + r;
          if (row < N)
            Y1[(size_t)row * HC + colg] = (unsigned short)rtn_bf16(acc[i][j][r] + bv);
        }
    } else {
      int cc = colg - HC;
      float bv = br[cc];
#pragma unroll
      for (int i = 0; i < 4; i++)
#pragma unroll
        for (int r = 0; r < 4; r++) {
          int row = row0 + wr + i * 16 + quad * 4 + r;
          if (row < N) Y2[(size_t)row * HC + cc] = acc[i][j][r] + bv;
        }
    }
  }
}

// ---------- CSR build ----------
__global__ __launch_bounds__(256) void hist_dst(
    const int* __restrict__ edst, int* __restrict__ counts, int E) {
  int e = blockIdx.x * 256 + threadIdx.x;
  if (e < E) atomicAdd(&counts[edst[e]], 1);
}

__global__ __launch_bounds__(256) void scan_blocks(
    const int* __restrict__ counts, int* __restrict__ row_start,
    int* __restrict__ bsum, int N) {
  __shared__ int tmp[256];
  int t = threadIdx.x;
  int base = blockIdx.x * 1024 + t * 4;
  int v0 = (base     < N) ? counts[base]     + 1 : 0;
  int v1 = (base + 1 < N) ? counts[base + 1] + 1 : 0;
  int v2 = (base + 2 < N) ? counts[base + 2] + 1 : 0;
  int v3 = (base + 3 < N) ? counts[base + 3] + 1 : 0;
  int c1 = v0 + v1, c2 = c1 + v2, tot = c2 + v3;
  tmp[t] = tot;
  __syncthreads();
  for (int off = 1; off < 256; off <<= 1) {
    int add = (t >= off) ? tmp[t - off] : 0;
    __syncthreads();
    tmp[t] += add;
    __syncthreads();
  }
  int excl = tmp[t] - tot;
  if (base     < N) row_start[base + 1] = excl + v0;
  if (base + 1 < N) row_start[base + 2] = excl + c1;
  if (base + 2 < N) row_start[base + 3] = excl + c2;
  if (base + 3 < N) row_start[base + 4] = excl + tot;
  if (t == 255) bsum[blockIdx.x] = tmp[255];
  if (blockIdx.x == 0 && t == 0) row_start[0] = 0;
}

__global__ void scan_tops(int* __restrict__ bsum, int nb) {
  int lane = threadIdx.x;
  int v = (lane < nb) ? bsum[lane] : 0;
  for (int off = 1; off < 64; off <<= 1) {
    int u = __shfl_up(v, off);
    if (lane >= off) v += u;
  }
  if (lane < nb) bsum[lane] = v;
}

__global__ __launch_bounds__(256) void scan_add(
    int* __restrict__ row_start, const int* __restrict__ bsum, int N) {
  int off = bsum[blockIdx.x];
  int i = (blockIdx.x + 1) * 1024 + threadIdx.x * 4;
#pragma unroll
  for (int k = 0; k < 4; k++)
    if (i + k < N) row_start[i + k + 1] += off;
}

__global__ __launch_bounds__(256) void csr_init(
    const int* __restrict__ row_start, int* __restrict__ fill_pos,
    int* __restrict__ csr_src, int N) {
  int i = blockIdx.x * 256 + threadIdx.x;
  if (i < N) {
    int p = row_start[i];
    csr_src[p] = i;
    fill_pos[i] = p + 1;
  }
}

__global__ __launch_bounds__(256) void csr_scatter(
    const int* __restrict__ esrc, const int* __restrict__ edst,
    int* __restrict__ fill_pos, int* __restrict__ csr_src, int E) {
  int e = blockIdx.x * 256 + threadIdx.x;
  if (e < E) {
    int p = atomicAdd(&fill_pos[edst[e]], 1);
    csr_src[p] = esrc[e];
  }
}

// ---------- fused GATv2 edge phase ----------
__device__ __forceinline__ float4 unpack_bf16x4(uint2 q) {
  float4 r;
  r.x = __uint_as_float(q.x << 16);
  r.y = __uint_as_float(q.x & 0xFFFF0000u);
  r.z = __uint_as_float(q.y << 16);
  r.w = __uint_as_float(q.y & 0xFFFF0000u);
  return r;
}

__device__ __forceinline__ float edge_dot(const float4 lv, const float4 rv, const float4 a) {
  float t, d = 0.f;
  t = lv.x + rv.x; t = t > 0.f ? t : NEG_ATT * t; d = fmaf(t, a.x, d);
  t = lv.y + rv.y; t = t > 0.f ? t : NEG_ATT * t; d = fmaf(t, a.y, d);
  t = lv.z + rv.z; t = t > 0.f ? t : NEG_ATT * t; d = fmaf(t, a.z, d);
  t = lv.w + rv.w; t = t > 0.f ? t : NEG_ATT * t; d = fmaf(t, a.w, d);
  d += __shfl_xor(d, 1);
  d += __shfl_xor(d, 2);
  d += __shfl_xor(d, 4);
  d += __shfl_xor(d, 8);
  return d;
}

__global__ __launch_bounds__(256) void gat_fused(
    const unsigned short* __restrict__ xl, const float* __restrict__ xr,
    const int* __restrict__ row_start, const int* __restrict__ csr_src,
    const float* __restrict__ att, const float* __restrict__ bo,
    float* __restrict__ outf, unsigned short* __restrict__ ohi,
    unsigned short* __restrict__ olo, int N, int split_out) {
  int dst = (blockIdx.x * 256 + threadIdx.x) >> 6;
  int lane = threadIdx.x & 63;
  if (dst >= N) return;
  int h = lane >> 4;
  int off = h * CH + (lane & 15) * 4;
  const float4 a = *(const float4*)&att[off];
  const float4 rv = *(const float4*)&xr[(size_t)dst * HC + off];
  float4 o = {0.f, 0.f, 0.f, 0.f};
  float m = -__builtin_inff();
  float s = 0.f;
  int p = row_start[dst];
  int end = row_start[dst + 1];
  for (; p + 4 <= end; p += 4) {
    int s0 = csr_src[p + 0], s1 = csr_src[p + 1];
    int s2 = csr_src[p + 2], s3 = csr_src[p + 3];
    const float4 lv0 = unpack_bf16x4(*(const uint2*)&xl[(size_t)s0 * HC + off]);
    const float4 lv1 = unpack_bf16x4(*(const uint2*)&xl[(size_t)s1 * HC + off]);
    const float4 lv2 = unpack_bf16x4(*(const uint2*)&xl[(size_t)s2 * HC + off]);
    const float4 lv3 = unpack_bf16x4(*(const uint2*)&xl[(size_t)s3 * HC + off]);
    float d0 = edge_dot(lv0, rv, a);
    float d1 = edge_dot(lv1, rv, a);
    float d2 = edge_dot(lv2, rv, a);
    float d3 = edge_dot(lv3, rv, a);
    float newm = fmaxf(fmaxf(fmaxf(d0, d1), fmaxf(d2, d3)), m);
    float sc = __expf(m - newm);
    float e0 = __expf(d0 - newm), e1 = __expf(d1 - newm);
    float e2 = __expf(d2 - newm), e3 = __expf(d3 - newm);
    s = fmaf(s, sc, (e0 + e1) + (e2 + e3));
    o.x = fmaf(o.x, sc, fmaf(e0, lv0.x, fmaf(e1, lv1.x, fmaf(e2, lv2.x, e3 * lv3.x))));
    o.y = fmaf(o.y, sc, fmaf(e0, lv0.y, fmaf(e1, lv1.y, fmaf(e2, lv2.y, e3 * lv3.y))));
    o.z = fmaf(o.z, sc, fmaf(e0, lv0.z, fmaf(e1, lv1.z, fmaf(e2, lv2.z, e3 * lv3.z))));
    o.w = fmaf(o.w, sc, fmaf(e0, lv0.w, fmaf(e1, lv1.w, fmaf(e2, lv2.w, e3 * lv3.w))));
    m = newm;
  }
  for (; p < end; p++) {
    int src = csr_src[p];
    const float4 lv = unpack_bf16x4(*(const uint2*)&xl[(size_t)src * HC + off]);
    float d = edge_dot(lv, rv, a);
    float newm = fmaxf(m, d);
    float sc = __expf(m - newm);
    float pe = __expf(d - newm);
    s = fmaf(s, sc, pe);
    o.x = fmaf(o.x, sc, pe * lv.x);
    o.y = fmaf(o.y, sc, pe * lv.y);
    o.z = fmaf(o.z, sc, pe * lv.z);
    o.w = fmaf(o.w, sc, pe * lv.w);
    m = newm;
  }
  float inv = 1.f / s;
  const float4 b4 = *(const float4*)&bo[off];
  float4 res;
  res.x = fmaf(o.x, inv, b4.x);
  res.y = fmaf(o.y, inv, b4.y);
  res.z = fmaf(o.z, inv, b4.z);
  res.w = fmaf(o.w, inv, b4.w);
  if (split_out) {
    res.x = res.x > 0.f ? res.x : NEG_ACT * res.x;
    res.y = res.y > 0.f ? res.y : NEG_ACT * res.y;
    res.z = res.z > 0.f ? res.z : NEG_ACT * res.z;
    res.w = res.w > 0.f ? res.w : NEG_ACT * res.w;
    uint2 h2, l2;
    split2(res.x, res.y, h2.x, l2.x);
    split2(res.z, res.w, h2.y, l2.y);
    *(uint2*)&ohi[(size_t)dst * HC + off] = h2;
    *(uint2*)&olo[(size_t)dst * HC + off] = l2;
  } else {
    *(float4*)&outf[(size_t)dst * HC + off] = res;
  }
}

// ---------- pooling ----------
__global__ __launch_bounds__(256) void pool_partial(
    const float* __restrict__ h, const int* __restrict__ batch,
    float* __restrict__ out, int* __restrict__ cnt, int N) {
  __shared__ float part[NGRAPH][HC];
  __shared__ int bsh[256];
  __shared__ int cpart[NGRAPH];
  int j = threadIdx.x;
#pragma unroll
  for (int g = 0; g < NGRAPH; g++) part[g][j] = 0.f;
  if (j < NGRAPH) cpart[j] = 0;
  int n0 = blockIdx.x * 256;
  int nend = min(n0 + 256, N);
  int nj = n0 + j;
  bsh[j] = (nj < N) ? batch[nj] : 0;
  __syncthreads();
  if (nj < nend) atomicAdd(&cpart[bsh[j]], 1);
  for (int n = n0; n < nend; n++) {
    int g = bsh[n - n0];
    part[g][j] += h[(size_t)n * HC + j];
  }
  __syncthreads();
#pragma unroll
  for (int g = 0; g < NGRAPH; g++) {
    float v = part[g][j];
    if (v != 0.f) atomicAdd(&out[g * HC + j], v);
  }
  if (j < NGRAPH && cpart[j] > 0) atomicAdd(&cnt[j], cpart[j]);
}

__global__ __launch_bounds__(256) void pool_final(
    float* __restrict__ out, const int* __restrict__ cnt) {
  int g = blockIdx.x;
  int j = threadIdx.x;
  float c = (float)max(cnt[g], 1);
  out[g * HC + j] /= c;
}

extern "C" void kernel_launch(void* const* d_in, const int* in_sizes, int n_in,
                              void* d_out, int out_size, void* d_ws, size_t ws_size,
                              hipStream_t stream) {
  const float* x = (const float*)d_in[0];
  const int* ei = (const int*)d_in[1];
  const int* batch = (const int*)d_in[2];
  const int N = in_sizes[2];
  const int E = in_sizes[1] / 2;
  const int Etot = E + N;

  const float* Wl[3] = {(const float*)d_in[3], (const float*)d_in[9], (const float*)d_in[15]};
  const float* bl[3] = {(const float*)d_in[4], (const float*)d_in[10], (const float*)d_in[16]};
  const float* Wr[3] = {(const float*)d_in[5], (const float*)d_in[11], (const float*)d_in[17]};
  const float* br[3] = {(const float*)d_in[6], (const float*)d_in[12], (const float*)d_in[18]};
  const float* att[3] = {(const float*)d_in[7], (const float*)d_in[13], (const float*)d_in[19]};
  const float* bo[3] = {(const float*)d_in[8], (const float*)d_in[14], (const float*)d_in[20]};

  // ws layout
  float* B0 = (float*)d_ws;                 // planes region (layers 1-2) / fp32 h3 (layer 3)
  float* B1 = B0 + (size_t)N * HC;          // xl (bf16, half the slot)
  float* B2 = B1 + (size_t)N * HC;          // xr (fp32)
  unsigned short* w1hi = (unsigned short*)(B2 + (size_t)N * HC);
  unsigned short* w1lo = w1hi + 512 * 128;
  unsigned short* w2hi = w1lo + 512 * 128;
  unsigned short* w2lo = w2hi + 512 * 256;
  unsigned short* w3hi = w2lo + 512 * 256;
  unsigned short* w3lo = w3hi + 512 * 256;
  int* counts = (int*)(w3lo + 512 * 256);
  int* row_start = counts + N;
  int* bsum = row_start + N + 1;
  int* fill_pos = bsum + 64;
  int* csr_src = fill_pos + N;
  int* cnt = csr_src + Etot;

  unsigned short* xlB = (unsigned short*)B1;
  unsigned short* xhiL1 = (unsigned short*)B0;
  unsigned short* xloL1 = xhiL1 + (size_t)N * 128;
  unsigned short* xhiL = (unsigned short*)B0;
  unsigned short* xloL = xhiL + (size_t)N * HC;

  const int* esrc = ei;
  const int* edst = ei + E;

  // ---- conversions ----
  convert_x<<<(N * 128 / 4 + 255) / 256, 256, 0, stream>>>(x, xhiL1, xloL1, N * 128 / 4);
  convert_w_frag<<<128 * 64 / 256, 256, 0, stream>>>(Wl[0], Wr[0], w1hi, w1lo, 128);
  convert_w_frag<<<256 * 64 / 256, 256, 0, stream>>>(Wl[1], Wr[1], w2hi, w2lo, 256);
  convert_w_frag<<<256 * 64 / 256, 256, 0, stream>>>(Wl[2], Wr[2], w3hi, w3lo, 256);

  // ---- CSR build ----
  const int nscan = (N + 1023) / 1024;
  (void)hipMemsetAsync(counts, 0, (size_t)N * sizeof(int), stream);
  hist_dst<<<(E + 255) / 256, 256, 0, stream>>>(edst, counts, E);
  scan_blocks<<<nscan, 256, 0, stream>>>(counts, row_start, bsum, N);
  scan_tops<<<1, 64, 0, stream>>>(bsum, nscan);
  scan_add<<<nscan - 1, 256, 0, stream>>>(row_start, bsum, N);
  csr_init<<<(N + 255) / 256, 256, 0, stream>>>(row_start, fill_pos, csr_src, N);
  csr_scatter<<<(E + 255) / 256, 256, 0, stream>>>(esrc, edst, fill_pos, csr_src, E);

  const dim3 ggrid(4, (N + 127) / 128);
  const int fblocks = (N * 64 + 255) / 256;

  // layer 1 (K=128)
  gemm_fused<<<ggrid, 256, 0, stream>>>(xhiL1, xloL1, w1hi, w1lo, bl[0], br[0], xlB, B2, N, 128);
  gat_fused<<<fblocks, 256, 0, stream>>>(xlB, B2, row_start, csr_src, att[0], bo[0],
                                         nullptr, xhiL, xloL, N, 1);
  // layer 2 (K=256)
  gemm_fused<<<ggrid, 256, 0, stream>>>(xhiL, xloL, w2hi, w2lo, bl[1], br[1], xlB, B2, N, 256);
  gat_fused<<<fblocks, 256, 0, stream>>>(xlB, B2, row_start, csr_src, att[1], bo[1],
                                         nullptr, xhiL, xloL, N, 1);
  // layer 3 (K=256), fp32 out for pooling
  gemm_fused<<<ggrid, 256, 0, stream>>>(xhiL, xloL, w3hi, w3lo, bl[2], br[2], xlB, B2, N, 256);
  gat_fused<<<fblocks, 256, 0, stream>>>(xlB, B2, row_start, csr_src, att[2], bo[2],
                                         B0, nullptr, nullptr, N, 0);

  (void)hipMemsetAsync(d_out, 0, NGRAPH * HC * sizeof(float), stream);
  (void)hipMemsetAsync(cnt, 0, NGRAPH * sizeof(int), stream);
  pool_partial<<<(N + 255) / 256, 256, 0, stream>>>(B0, batch, (float*)d_out, cnt, N);
  pool_final<<<NGRAPH, 256, 0, stream>>>((float*)d_out, cnt);
}

// Round 7
// 692.076 us; speedup vs baseline: 14.8578x; 1.0060x over previous
//
#include <hip/hip_runtime.h>

#define HEADS 4
#define CH 64
#define HC 256
#define NGRAPH 32
#define NEG_ATT 0.2f
#define NEG_ACT 0.01f

typedef __attribute__((ext_vector_type(8))) short bf16x8;
typedef __attribute__((ext_vector_type(4))) float f32x4;
typedef __attribute__((ext_vector_type(2))) float f32x2;

typedef __attribute__((address_space(3))) unsigned int lds_u32;
typedef const __attribute__((address_space(1))) unsigned int glob_u32;

// async global->LDS, 16B per lane; LDS dest = wave-uniform base + lane*16
__device__ __forceinline__ void gl_lds16(const void* g, void* l) {
  __builtin_amdgcn_global_load_lds((glob_u32*)(uintptr_t)g,
                                   (lds_u32*)(unsigned int)(uintptr_t)l, 16, 0, 0);
}

// split two fp32 into packed hi-bf16 pair and lo-bf16 pair (truncation; lo captures residual)
__device__ __forceinline__ void split2(float a, float b, unsigned& hi, unsigned& lo) {
  unsigned ua = __float_as_uint(a), ub = __float_as_uint(b);
  float la = a - __uint_as_float(ua & 0xFFFF0000u);
  float lb = b - __uint_as_float(ub & 0xFFFF0000u);
  hi = __builtin_amdgcn_perm(ub, ua, 0x07060302u);  // [hi16(b) : hi16(a)]
  lo = __builtin_amdgcn_perm(__float_as_uint(lb), __float_as_uint(la), 0x07060302u);
}

// round-to-nearest-even fp32 -> bf16 (low 16 bits)
__device__ __forceinline__ unsigned rtn_bf16(float f) {
  unsigned u = __float_as_uint(f);
  return (u + 0x7FFFu + ((u >> 16) & 1u)) >> 16;
}

// ---------- conversions ----------
__global__ __launch_bounds__(256) void convert_x(
    const float* __restrict__ X, unsigned short* __restrict__ xhi,
    unsigned short* __restrict__ xlo, int total4) {
  int g = blockIdx.x * 256 + threadIdx.x;
  if (g >= total4) return;
  float4 v = *(const float4*)&X[(size_t)g * 4];
  uint2 h2, l2;
  split2(v.x, v.y, h2.x, l2.x);
  split2(v.z, v.w, h2.y, l2.y);
  *(uint2*)&xhi[(size_t)g * 4] = h2;
  *(uint2*)&xlo[(size_t)g * 4] = l2;
}

// W' = [Wl; Wr] (512 x K) -> MFMA-fragment-ordered hi/lo planes.
// chunk ci = (kb*32 + ct)*64 + lane holds W'[ct*16 + (lane&15)][kb*32 + (lane>>4)*8 .. +8]
__global__ __launch_bounds__(256) void convert_w_frag(
    const float* __restrict__ Wl, const float* __restrict__ Wr,
    unsigned short* __restrict__ wfhi, unsigned short* __restrict__ wflo, int K) {
  int g = blockIdx.x * 256 + threadIdx.x;  // K*64 chunks
  int lane = g & 63;
  int ct = (g >> 6) & 31;
  int kb = g >> 11;
  int col = ct * 16 + (lane & 15);
  int k = kb * 32 + (lane >> 4) * 8;
  const float* src = (col < HC) ? &Wl[(size_t)col * K + k] : &Wr[(size_t)(col - HC) * K + k];
  float4 v0 = *(const float4*)src;
  float4 v1 = *(const float4*)(src + 4);
  uint4 hq, lq;
  split2(v0.x, v0.y, hq.x, lq.x);
  split2(v0.z, v0.w, hq.y, lq.y);
  split2(v1.x, v1.y, hq.z, lq.z);
  split2(v1.z, v1.w, hq.w, lq.w);
  *(uint4*)&wfhi[(size_t)g * 8] = hq;
  *(uint4*)&wflo[(size_t)g * 8] = lq;
}

// ---------- MFMA GEMM: [xl(bf16) | xr(fp32)] = X(hi/lo) @ W'(hi/lo)^T + bias ----------
// 128x128 per block, 4 waves. A: double-buffered LDS via global_load_lds.
// B: fragment-ordered global loads, double-buffered in registers, prefetched under MFMA.
template <int K>
__global__ __launch_bounds__(256) void gemm_fused(
    const unsigned short* __restrict__ xhi, const unsigned short* __restrict__ xlo,
    const unsigned short* __restrict__ wfhi, const unsigned short* __restrict__ wflo,
    const float* __restrict__ bl, const float* __restrict__ br,
    unsigned short* __restrict__ Y1, float* __restrict__ Y2, int N) {
  constexpr int nkb = K >> 5;
  __shared__ unsigned short Ah[2][128][32];
  __shared__ unsigned short Al[2][128][32];

  const int tid = threadIdx.x;
  const int wave = tid >> 6;
  const int lane = tid & 63;
  const int quad = lane >> 4;
  const int l16 = lane & 15;
  const int wr = (wave >> 1) * 64;
  const int wc = (wave & 1) * 64;
  const int col0 = blockIdx.x * 128;
  const int row0 = blockIdx.y * 128;
  const int ctg0 = blockIdx.x * 8 + (wave & 1) * 4;  // wave's first col-tile (global)

  // staging addresses for this thread (2 chunks per plane)
  const int c0 = tid, c1 = tid + 256;
  const int r0g = row0 + (c0 >> 2), r1g = row0 + (c1 >> 2);
  const int ko0 = (c0 & 3) * 8, ko1 = (c1 & 3) * 8;
  const int gr0 = (r0g < N) ? r0g : N - 1;
  const int gr1 = (r1g < N) ? r1g : N - 1;

  f32x4 acc[4][4];
#pragma unroll
  for (int i = 0; i < 4; i++)
#pragma unroll
    for (int j = 0; j < 4; j++) acc[i][j] = (f32x4){0.f, 0.f, 0.f, 0.f};

  // prologue: B fragments for k-tile 0, stage A k-tile 0 into buffer 0
  bf16x8 bhi[2][4], blo[2][4];
#pragma unroll
  for (int j = 0; j < 4; j++) {
    size_t ci = (size_t)(ctg0 + j) * 64 + lane;
    bhi[0][j] = *(const bf16x8*)&wfhi[ci * 8];
    blo[0][j] = *(const bf16x8*)&wflo[ci * 8];
  }
  {
    size_t ga0 = (size_t)gr0 * K + ko0;
    size_t ga1 = (size_t)gr1 * K + ko1;
    gl_lds16(&xhi[ga0], &Ah[0][c0 >> 2][ko0]);
    gl_lds16(&xlo[ga0], &Al[0][c0 >> 2][ko0]);
    gl_lds16(&xhi[ga1], &Ah[0][c1 >> 2][ko1]);
    gl_lds16(&xlo[ga1], &Al[0][c1 >> 2][ko1]);
  }

#pragma unroll
  for (int kb = 0; kb < nkb; kb++) {
    const int cur = kb & 1, nxt = cur ^ 1;
    __syncthreads();  // drains staging(kb) + B(kb) prefetch from prior iter
    if (kb + 1 < nkb) {
      int k0 = (kb + 1) * 32;
      size_t ga0 = (size_t)gr0 * K + k0 + ko0;
      size_t ga1 = (size_t)gr1 * K + k0 + ko1;
      gl_lds16(&xhi[ga0], &Ah[nxt][c0 >> 2][ko0]);
      gl_lds16(&xlo[ga0], &Al[nxt][c0 >> 2][ko0]);
      gl_lds16(&xhi[ga1], &Ah[nxt][c1 >> 2][ko1]);
      gl_lds16(&xlo[ga1], &Al[nxt][c1 >> 2][ko1]);
    }
    bf16x8 ahi[4], alo[4];
#pragma unroll
    for (int i = 0; i < 4; i++) {
      ahi[i] = *(const bf16x8*)&Ah[cur][wr + i * 16 + l16][quad * 8];
      alo[i] = *(const bf16x8*)&Al[cur][wr + i * 16 + l16][quad * 8];
    }
    if (kb + 1 < nkb) {  // prefetch B(kb+1) under the MFMAs
#pragma unroll
      for (int j = 0; j < 4; j++) {
        size_t ci = ((size_t)(kb + 1) * 32 + ctg0 + j) * 64 + lane;
        bhi[nxt][j] = *(const bf16x8*)&wfhi[ci * 8];
        blo[nxt][j] = *(const bf16x8*)&wflo[ci * 8];
      }
    }
#pragma unroll
    for (int i = 0; i < 4; i++)
#pragma unroll
      for (int j = 0; j < 4; j++) {
        acc[i][j] = __builtin_amdgcn_mfma_f32_16x16x32_bf16(ahi[i], bhi[cur][j], acc[i][j], 0, 0, 0);
        acc[i][j] = __builtin_amdgcn_mfma_f32_16x16x32_bf16(ahi[i], blo[cur][j], acc[i][j], 0, 0, 0);
        acc[i][j] = __builtin_amdgcn_mfma_f32_16x16x32_bf16(alo[i], bhi[cur][j], acc[i][j], 0, 0, 0);
      }
  }

  // epilogue: D row = quad*4+reg, col = l16; xl -> bf16 (RTN), xr -> fp32
#pragma unroll
  for (int j = 0; j < 4; j++) {
    int colg = col0 + wc + j * 16 + l16;  // 0..511
    if (colg < HC) {
      float bv = bl[colg];
#pragma unroll
      for (int i = 0; i < 4; i++)
#pragma unroll
        for (int r = 0; r < 4; r++) {
          int row = row0 + wr + i * 16 + quad * 4 + r;
          if (row < N)
            Y1[(size_t)row * HC + colg] = (unsigned short)rtn_bf16(acc[i][j][r] + bv);
        }
    } else {
      int cc = colg - HC;
      float bv = br[cc];
#pragma unroll
      for (int i = 0; i < 4; i++)
#pragma unroll
        for (int r = 0; r < 4; r++) {
          int row = row0 + wr + i * 16 + quad * 4 + r;
          if (row < N) Y2[(size_t)row * HC + cc] = acc[i][j][r] + bv;
        }
    }
  }
}

// ---------- CSR build (csr_src holds BYTE offsets into bf16 xl: src*512) ----------
__global__ __launch_bounds__(256) void hist_dst(
    const int* __restrict__ edst, int* __restrict__ counts, int E) {
  int e = blockIdx.x * 256 + threadIdx.x;
  if (e < E) atomicAdd(&counts[edst[e]], 1);
}

__global__ __launch_bounds__(256) void scan_blocks(
    const int* __restrict__ counts, int* __restrict__ row_start,
    int* __restrict__ bsum, int N) {
  __shared__ int tmp[256];
  int t = threadIdx.x;
  int base = blockIdx.x * 1024 + t * 4;
  int v0 = (base     < N) ? counts[base]     + 1 : 0;
  int v1 = (base + 1 < N) ? counts[base + 1] + 1 : 0;
  int v2 = (base + 2 < N) ? counts[base + 2] + 1 : 0;
  int v3 = (base + 3 < N) ? counts[base + 3] + 1 : 0;
  int c1 = v0 + v1, c2 = c1 + v2, tot = c2 + v3;
  tmp[t] = tot;
  __syncthreads();
  for (int off = 1; off < 256; off <<= 1) {
    int add = (t >= off) ? tmp[t - off] : 0;
    __syncthreads();
    tmp[t] += add;
    __syncthreads();
  }
  int excl = tmp[t] - tot;
  if (base     < N) row_start[base + 1] = excl + v0;
  if (base + 1 < N) row_start[base + 2] = excl + c1;
  if (base + 2 < N) row_start[base + 3] = excl + c2;
  if (base + 3 < N) row_start[base + 4] = excl + tot;
  if (t == 255) bsum[blockIdx.x] = tmp[255];
  if (blockIdx.x == 0 && t == 0) row_start[0] = 0;
}

__global__ void scan_tops(int* __restrict__ bsum, int nb) {
  int lane = threadIdx.x;
  int v = (lane < nb) ? bsum[lane] : 0;
  for (int off = 1; off < 64; off <<= 1) {
    int u = __shfl_up(v, off);
    if (lane >= off) v += u;
  }
  if (lane < nb) bsum[lane] = v;
}

__global__ __launch_bounds__(256) void scan_add(
    int* __restrict__ row_start, const int* __restrict__ bsum, int N) {
  int off = bsum[blockIdx.x];
  int i = (blockIdx.x + 1) * 1024 + threadIdx.x * 4;
#pragma unroll
  for (int k = 0; k < 4; k++)
    if (i + k < N) row_start[i + k + 1] += off;
}

__global__ __launch_bounds__(256) void csr_init(
    const int* __restrict__ row_start, int* __restrict__ fill_pos,
    int* __restrict__ csr_src, int N) {
  int i = blockIdx.x * 256 + threadIdx.x;
  if (i < N) {
    int p = row_start[i];
    csr_src[p] = i << 9;  // self-loop first, byte offset
    fill_pos[i] = p + 1;
  }
}

__global__ __launch_bounds__(256) void csr_scatter(
    const int* __restrict__ esrc, const int* __restrict__ edst,
    int* __restrict__ fill_pos, int* __restrict__ csr_src, int E) {
  int e = blockIdx.x * 256 + threadIdx.x;
  if (e < E) {
    int p = atomicAdd(&fill_pos[edst[e]], 1);
    csr_src[p] = esrc[e] << 9;  // byte offset
  }
}

// ---------- fused GATv2 edge phase: packed-f32 math, byte-offset gather ----------
__device__ __forceinline__ void unpk(uint2 q, f32x2& v01, f32x2& v23) {
  v01.x = __uint_as_float(q.x << 16);
  v01.y = __uint_as_float(q.x & 0xFFFF0000u);
  v23.x = __uint_as_float(q.y << 16);
  v23.y = __uint_as_float(q.y & 0xFFFF0000u);
}

__device__ __forceinline__ float edot(f32x2 l01, f32x2 l23, f32x2 r01, f32x2 r23,
                                      f32x2 a01, f32x2 a23) {
  f32x2 t01 = l01 + r01, t23 = l23 + r23;       // v_pk_add_f32
  f32x2 u01 = t01 * NEG_ATT, u23 = t23 * NEG_ATT;  // v_pk_mul_f32
  t01.x = fmaxf(t01.x, u01.x); t01.y = fmaxf(t01.y, u01.y);  // leaky = max(t,0.2t)
  t23.x = fmaxf(t23.x, u23.x); t23.y = fmaxf(t23.y, u23.y);
  f32x2 dv = t01 * a01 + t23 * a23;             // pk_mul + pk_fma
  float d = dv.x + dv.y;
  d += __shfl_xor(d, 1);
  d += __shfl_xor(d, 2);
  d += __shfl_xor(d, 4);
  d += __shfl_xor(d, 8);
  return d;
}

__global__ __launch_bounds__(256) void gat_fused(
    const unsigned short* __restrict__ xl, const float* __restrict__ xr,
    const int* __restrict__ row_start, const int* __restrict__ csr_soff,
    const float* __restrict__ att, const float* __restrict__ bo,
    float* __restrict__ outf, unsigned short* __restrict__ ohi,
    unsigned short* __restrict__ olo, int N, int split_out) {
  int dst = (blockIdx.x * 256 + threadIdx.x) >> 6;
  int lane = threadIdx.x & 63;
  if (dst >= N) return;
  int h = lane >> 4;
  int off = h * CH + (lane & 15) * 4;
  const int loff = off * 2;  // byte offset of this lane's 4 bf16 channels
  const char* xlc = (const char*)xl;
  f32x2 a01 = *(const f32x2*)&att[off];
  f32x2 a23 = *(const f32x2*)&att[off + 2];
  f32x2 r01 = *(const f32x2*)&xr[(size_t)dst * HC + off];
  f32x2 r23 = *(const f32x2*)&xr[(size_t)dst * HC + off + 2];
  f32x2 o01 = {0.f, 0.f}, o23 = {0.f, 0.f};
  float m = -__builtin_inff();
  float s = 0.f;
  int p = row_start[dst];
  int end = row_start[dst + 1];
  for (; p + 4 <= end; p += 4) {
    int b0 = csr_soff[p + 0] + loff, b1 = csr_soff[p + 1] + loff;
    int b2 = csr_soff[p + 2] + loff, b3 = csr_soff[p + 3] + loff;
    uint2 q0 = *(const uint2*)(xlc + b0);
    uint2 q1 = *(const uint2*)(xlc + b1);
    uint2 q2 = *(const uint2*)(xlc + b2);
    uint2 q3 = *(const uint2*)(xlc + b3);
    f32x2 l0a, l0b, l1a, l1b, l2a, l2b, l3a, l3b;
    unpk(q0, l0a, l0b);
    unpk(q1, l1a, l1b);
    unpk(q2, l2a, l2b);
    unpk(q3, l3a, l3b);
    float d0 = edot(l0a, l0b, r01, r23, a01, a23);
    float d1 = edot(l1a, l1b, r01, r23, a01, a23);
    float d2 = edot(l2a, l2b, r01, r23, a01, a23);
    float d3 = edot(l3a, l3b, r01, r23, a01, a23);
    float newm = fmaxf(fmaxf(fmaxf(d0, d1), fmaxf(d2, d3)), m);
    float sc = __expf(m - newm);
    float e0 = __expf(d0 - newm), e1 = __expf(d1 - newm);
    float e2 = __expf(d2 - newm), e3 = __expf(d3 - newm);
    s = fmaf(s, sc, (e0 + e1) + (e2 + e3));
    f32x2 acc01 = l0a * e0 + l1a * e1;
    acc01 = l2a * e2 + acc01;
    acc01 = l3a * e3 + acc01;
    o01 = o01 * sc + acc01;
    f32x2 acc23 = l0b * e0 + l1b * e1;
    acc23 = l2b * e2 + acc23;
    acc23 = l3b * e3 + acc23;
    o23 = o23 * sc + acc23;
    m = newm;
  }
  for (; p < end; p++) {
    int b0 = csr_soff[p] + loff;
    uint2 q0 = *(const uint2*)(xlc + b0);
    f32x2 la, lb;
    unpk(q0, la, lb);
    float d = edot(la, lb, r01, r23, a01, a23);
    float newm = fmaxf(m, d);
    float sc = __expf(m - newm);
    float pe = __expf(d - newm);
    s = fmaf(s, sc, pe);
    o01 = o01 * sc + la * pe;
    o23 = o23 * sc + lb * pe;
    m = newm;
  }
  float inv = 1.f / s;
  f32x2 b01 = *(const f32x2*)&bo[off];
  f32x2 b23 = *(const f32x2*)&bo[off + 2];
  f32x2 res01 = o01 * inv + b01;
  f32x2 res23 = o23 * inv + b23;
  if (split_out) {
    f32x2 v01 = res01 * NEG_ACT, v23 = res23 * NEG_ACT;
    res01.x = fmaxf(res01.x, v01.x); res01.y = fmaxf(res01.y, v01.y);
    res23.x = fmaxf(res23.x, v23.x); res23.y = fmaxf(res23.y, v23.y);
    uint2 h2, l2;
    split2(res01.x, res01.y, h2.x, l2.x);
    split2(res23.x, res23.y, h2.y, l2.y);
    *(uint2*)&ohi[(size_t)dst * HC + off] = h2;
    *(uint2*)&olo[(size_t)dst * HC + off] = l2;
  } else {
    float4 r4 = {res01.x, res01.y, res23.x, res23.y};
    *(float4*)&outf[(size_t)dst * HC + off] = r4;
  }
}

// ---------- pooling ----------
__global__ __launch_bounds__(256) void pool_partial(
    const float* __restrict__ h, const int* __restrict__ batch,
    float* __restrict__ out, int* __restrict__ cnt, int N) {
  __shared__ float part[NGRAPH][HC];
  __shared__ int bsh[256];
  __shared__ int cpart[NGRAPH];
  int j = threadIdx.x;
#pragma unroll
  for (int g = 0; g < NGRAPH; g++) part[g][j] = 0.f;
  if (j < NGRAPH) cpart[j] = 0;
  int n0 = blockIdx.x * 256;
  int nend = min(n0 + 256, N);
  int nj = n0 + j;
  bsh[j] = (nj < N) ? batch[nj] : 0;
  __syncthreads();
  if (nj < nend) atomicAdd(&cpart[bsh[j]], 1);
  for (int n = n0; n < nend; n++) {
    int g = bsh[n - n0];
    part[g][j] += h[(size_t)n * HC + j];
  }
  __syncthreads();
#pragma unroll
  for (int g = 0; g < NGRAPH; g++) {
    float v = part[g][j];
    if (v != 0.f) atomicAdd(&out[g * HC + j], v);
  }
  if (j < NGRAPH && cpart[j] > 0) atomicAdd(&cnt[j], cpart[j]);
}

__global__ __launch_bounds__(256) void pool_final(
    float* __restrict__ out, const int* __restrict__ cnt) {
  int g = blockIdx.x;
  int j = threadIdx.x;
  float c = (float)max(cnt[g], 1);
  out[g * HC + j] /= c;
}

extern "C" void kernel_launch(void* const* d_in, const int* in_sizes, int n_in,
                              void* d_out, int out_size, void* d_ws, size_t ws_size,
                              hipStream_t stream) {
  const float* x = (const float*)d_in[0];
  const int* ei = (const int*)d_in[1];
  const int* batch = (const int*)d_in[2];
  const int N = in_sizes[2];
  const int E = in_sizes[1] / 2;
  const int Etot = E + N;

  const float* Wl[3] = {(const float*)d_in[3], (const float*)d_in[9], (const float*)d_in[15]};
  const float* bl[3] = {(const float*)d_in[4], (const float*)d_in[10], (const float*)d_in[16]};
  const float* Wr[3] = {(const float*)d_in[5], (const float*)d_in[11], (const float*)d_in[17]};
  const float* br[3] = {(const float*)d_in[6], (const float*)d_in[12], (const float*)d_in[18]};
  const float* att[3] = {(const float*)d_in[7], (const float*)d_in[13], (const float*)d_in[19]};
  const float* bo[3] = {(const float*)d_in[8], (const float*)d_in[14], (const float*)d_in[20]};

  // ws layout
  float* B0 = (float*)d_ws;                 // planes region (layers 1-2) / fp32 h3 (layer 3)
  float* B1 = B0 + (size_t)N * HC;          // xl (bf16, half the slot)
  float* B2 = B1 + (size_t)N * HC;          // xr (fp32)
  unsigned short* w1hi = (unsigned short*)(B2 + (size_t)N * HC);
  unsigned short* w1lo = w1hi + 512 * 128;
  unsigned short* w2hi = w1lo + 512 * 128;
  unsigned short* w2lo = w2hi + 512 * 256;
  unsigned short* w3hi = w2lo + 512 * 256;
  unsigned short* w3lo = w3hi + 512 * 256;
  int* counts = (int*)(w3lo + 512 * 256);
  int* row_start = counts + N;
  int* bsum = row_start + N + 1;
  int* fill_pos = bsum + 64;
  int* csr_src = fill_pos + N;
  int* cnt = csr_src + Etot;

  unsigned short* xlB = (unsigned short*)B1;
  unsigned short* xhiL1 = (unsigned short*)B0;
  unsigned short* xloL1 = xhiL1 + (size_t)N * 128;
  unsigned short* xhiL = (unsigned short*)B0;
  unsigned short* xloL = xhiL + (size_t)N * HC;

  const int* esrc = ei;
  const int* edst = ei + E;

  // ---- conversions ----
  convert_x<<<(N * 128 / 4 + 255) / 256, 256, 0, stream>>>(x, xhiL1, xloL1, N * 128 / 4);
  convert_w_frag<<<128 * 64 / 256, 256, 0, stream>>>(Wl[0], Wr[0], w1hi, w1lo, 128);
  convert_w_frag<<<256 * 64 / 256, 256, 0, stream>>>(Wl[1], Wr[1], w2hi, w2lo, 256);
  convert_w_frag<<<256 * 64 / 256, 256, 0, stream>>>(Wl[2], Wr[2], w3hi, w3lo, 256);

  // ---- CSR build ----
  const int nscan = (N + 1023) / 1024;
  (void)hipMemsetAsync(counts, 0, (size_t)N * sizeof(int), stream);
  hist_dst<<<(E + 255) / 256, 256, 0, stream>>>(edst, counts, E);
  scan_blocks<<<nscan, 256, 0, stream>>>(counts, row_start, bsum, N);
  scan_tops<<<1, 64, 0, stream>>>(bsum, nscan);
  scan_add<<<nscan - 1, 256, 0, stream>>>(row_start, bsum, N);
  csr_init<<<(N + 255) / 256, 256, 0, stream>>>(row_start, fill_pos, csr_src, N);
  csr_scatter<<<(E + 255) / 256, 256, 0, stream>>>(esrc, edst, fill_pos, csr_src, E);

  const dim3 ggrid(4, (N + 127) / 128);
  const int fblocks = (N * 64 + 255) / 256;

  // layer 1 (K=128)
  gemm_fused<128><<<ggrid, 256, 0, stream>>>(xhiL1, xloL1, w1hi, w1lo, bl[0], br[0], xlB, B2, N);
  gat_fused<<<fblocks, 256, 0, stream>>>(xlB, B2, row_start, csr_src, att[0], bo[0],
                                         nullptr, xhiL, xloL, N, 1);
  // layer 2 (K=256)
  gemm_fused<256><<<ggrid, 256, 0, stream>>>(xhiL, xloL, w2hi, w2lo, bl[1], br[1], xlB, B2, N);
  gat_fused<<<fblocks, 256, 0, stream>>>(xlB, B2, row_start, csr_src, att[1], bo[1],
                                         nullptr, xhiL, xloL, N, 1);
  // layer 3 (K=256), fp32 out for pooling
  gemm_fused<256><<<ggrid, 256, 0, stream>>>(xhiL, xloL, w3hi, w3lo, bl[2], br[2], xlB, B2, N);
  gat_fused<<<fblocks, 256, 0, stream>>>(xlB, B2, row_start, csr_src, att[2], bo[2],
                                         B0, nullptr, nullptr, N, 0);

  (void)hipMemsetAsync(d_out, 0, NGRAPH * HC * sizeof(float), stream);
  (void)hipMemsetAsync(cnt, 0, NGRAPH * sizeof(int), stream);
  pool_partial<<<(N + 255) / 256, 256, 0, stream>>>(B0, batch, (float*)d_out, cnt, N);
  pool_final<<<NGRAPH, 256, 0, stream>>>((float*)d_out, cnt);
}